// Round 4
// baseline (2822.799 us; speedup 1.0000x reference)
//
#include <hip/hip_runtime.h>

#define NN 16384
#define NF 512
#define NH 64
#define NC 40
#define KSTEPS 10

typedef __attribute__((ext_vector_type(8))) short short8;
typedef __attribute__((ext_vector_type(4))) float f32x4;

__device__ __forceinline__ unsigned short f2bf(float f) {
    unsigned int u = __float_as_uint(f);
    u += 0x7FFFu + ((u >> 16) & 1u);   // RNE
    return (unsigned short)(u >> 16);
}
__device__ __forceinline__ float bf2f(unsigned short h) {
    return __uint_as_float((unsigned int)h << 16);
}
__device__ __forceinline__ short8 cvt8(f32x4 f0, f32x4 f1) {
    short8 r;
    r[0] = (short)f2bf(f0[0]); r[1] = (short)f2bf(f0[1]);
    r[2] = (short)f2bf(f0[2]); r[3] = (short)f2bf(f0[3]);
    r[4] = (short)f2bf(f1[0]); r[5] = (short)f2bf(f1[1]);
    r[6] = (short)f2bf(f1[2]); r[7] = (short)f2bf(f1[3]);
    return r;
}
// non-temporal (streaming) accessors: keep the 512 MiB A-stream from
// evicting the 2 MiB x-state out of L2
__device__ __forceinline__ short8 ntload_s8(const unsigned short* p) {
    return __builtin_nontemporal_load((const short8*)p);
}
__device__ __forceinline__ f32x4 ntload_f4(const float* p) {
    return __builtin_nontemporal_load((const f32x4*)p);
}
__device__ __forceinline__ void ntstore_s8(unsigned short* p, short8 v) {
    __builtin_nontemporal_store(v, (short8*)p);
}

// ---------------------------------------------------------------------------
// h0T[c][r] = relu(x @ W1)[r][c]  (bf16, transposed layout)
// ---------------------------------------------------------------------------
__global__ __launch_bounds__(256) void h0_kernel(const float* __restrict__ x,
                                                 const float* __restrict__ W1,
                                                 unsigned short* __restrict__ h0T) {
    const int t  = threadIdx.x;
    const int rl = t & 63;
    const int w  = t >> 6;
    const size_t r = (size_t)blockIdx.x * 64 + rl;
    const float* xr = x + r * NF;

    float acc[16];
#pragma unroll
    for (int j = 0; j < 16; ++j) acc[j] = 0.f;

    for (int k = 0; k < NF; k += 4) {
        f32x4 xv = *(const f32x4*)&xr[k];
#pragma unroll
        for (int i = 0; i < 4; ++i) {
            const float* wr = W1 + (size_t)(k + i) * NH + w * 16;
#pragma unroll
            for (int j = 0; j < 16; ++j) acc[j] = fmaf(xv[i], wr[j], acc[j]);
        }
    }
#pragma unroll
    for (int j = 0; j < 16; ++j)
        h0T[(size_t)(w * 16 + j) * NN + r] = f2bf(fmaxf(acc[j], 0.f));
}

// ---------------------------------------------------------------------------
// finish32: combine 8 per-wave K-partials (BM=32 kernels: step0 / fallback),
// fuse 0.9*s + 0.1*h0T, store bf16. pad 66 -> <=2-way (free) on reads.
// ---------------------------------------------------------------------------
__device__ __forceinline__ void finish32(float buf[8][32][66],
                                         const f32x4 (&acc)[2][4],
                                         int t, int l, int w, int row0,
                                         const unsigned short* __restrict__ h0T,
                                         unsigned short* __restrict__ xnT) {
    const int fr = l & 15;
    const int fg = l >> 4;
#pragma unroll
    for (int mi = 0; mi < 2; ++mi)
#pragma unroll
        for (int ni = 0; ni < 4; ++ni)
#pragma unroll
            for (int r = 0; r < 4; ++r)
                buf[w][16 * mi + 4 * fg + r][16 * ni + fr] = acc[mi][ni][r];
    __syncthreads();

    const int col = t >> 3;
    const int rb  = 4 * (t & 7);
    float s0 = 0.f, s1 = 0.f, s2 = 0.f, s3 = 0.f;
#pragma unroll
    for (int ww = 0; ww < 8; ++ww) {
        s0 += buf[ww][rb + 0][col];
        s1 += buf[ww][rb + 1][col];
        s2 += buf[ww][rb + 2][col];
        s3 += buf[ww][rb + 3][col];
    }
    const size_t base = (size_t)col * NN + row0 + rb;
    ushort4 h4 = *(const ushort4*)&h0T[base];
    ushort4 o;
    o.x = f2bf(0.9f * s0 + 0.1f * bf2f(h4.x));
    o.y = f2bf(0.9f * s1 + 0.1f * bf2f(h4.y));
    o.z = f2bf(0.9f * s2 + 0.1f * bf2f(h4.z));
    o.w = f2bf(0.9f * s3 + 0.1f * bf2f(h4.w));
    *(ushort4*)&xnT[base] = o;
}

// ---------------------------------------------------------------------------
// Step 0 (fused): read adj fp32 (nt), convert, MFMA, and store bf16 fragments
// to tiled adjT (nt): elem adj[rt*16+(l&15)][kt*64+32h+8*(l>>4)+j] at
// flat short idx ((rt*256+kt)*2+h)*512 + l*8 + j.
// ---------------------------------------------------------------------------
__global__ __launch_bounds__(512, 2) void step0_kernel(
        const float* __restrict__ adj,
        unsigned short* __restrict__ adjT,
        const unsigned short* __restrict__ xT,
        const unsigned short* __restrict__ h0T,
        unsigned short* __restrict__ xnT) {
    __shared__ float buf[8][32][66];

    const int t    = threadIdx.x;
    const int l    = t & 63;
    const int w    = t >> 6;
    const int fr   = l & 15;
    const int fg   = l >> 4;
    const int row0 = blockIdx.x * 32;

    const size_t a0 = (size_t)(row0 + fr) * NN;
    const size_t a1 = a0 + (size_t)16 * NN;
    const long   kbase = (long)w * (NN / 8) + 8 * fg;

    f32x4 acc[2][4];
#pragma unroll
    for (int mi = 0; mi < 2; ++mi)
#pragma unroll
        for (int ni = 0; ni < 4; ++ni) acc[mi][ni] = (f32x4){0.f, 0.f, 0.f, 0.f};

    for (int kk = 0; kk < NN / 8; kk += 64) {
        const long kb      = kbase + kk;
        const size_t ktile = (size_t)w * 32 + (kk >> 6);
        short8 a[2][2], b[4][2];

#pragma unroll
        for (int mi = 0; mi < 2; ++mi) {
            const size_t ab = (mi ? a1 : a0);
#pragma unroll
            for (int h = 0; h < 2; ++h) {
                f32x4 f0 = ntload_f4(&adj[ab + kb + 32 * h]);
                f32x4 f1 = ntload_f4(&adj[ab + kb + 32 * h + 4]);
                a[mi][h] = cvt8(f0, f1);
                const size_t st = ((size_t)(2 * blockIdx.x + mi) * 256 + ktile) * 1024
                                  + (size_t)h * 512 + (size_t)l * 8;
                ntstore_s8(&adjT[st], a[mi][h]);
            }
        }
#pragma unroll
        for (int ni = 0; ni < 4; ++ni)
#pragma unroll
            for (int h = 0; h < 2; ++h)
                b[ni][h] = *(const short8*)&xT[(size_t)(16 * ni + fr) * NN + kb + 32 * h];

#pragma unroll
        for (int mi = 0; mi < 2; ++mi)
#pragma unroll
            for (int ni = 0; ni < 4; ++ni)
#pragma unroll
                for (int h = 0; h < 2; ++h)
                    acc[mi][ni] = __builtin_amdgcn_mfma_f32_16x16x32_bf16(
                        a[mi][h], b[ni][h], acc[mi][ni], 0, 0, 0);
    }
    finish32(buf, acc, t, l, w, row0, h0T, xnT);
}

// ---------------------------------------------------------------------------
// Steps 1..9: BM=64, 4 waves (KSPLIT=4), wave = 4 m-tiles x 4 n-tiles,
// K-range 4096. A: 4 sequential nt streams of 1 KB coalesced loads.
// B: xT from L2 (protected by nt A). Barrier-free hot loop.
// Epilogue: two 32-row halves through a 34 KB pad-67 LDS buffer.
// ---------------------------------------------------------------------------
__global__ __launch_bounds__(256, 2) void stept_kernel(
        const unsigned short* __restrict__ adjT,
        const unsigned short* __restrict__ xT,
        const unsigned short* __restrict__ h0T,
        unsigned short* __restrict__ xnT) {
    __shared__ float buf[4][32][67];

    const int t    = threadIdx.x;
    const int l    = t & 63;
    const int w    = t >> 6;                 // 0..3 : K-split id
    const int fr   = l & 15;
    const int fg   = l >> 4;
    const int row0 = blockIdx.x * 64;

    const long kbase = (long)w * (NN / 4) + 8 * fg;
    const unsigned short* At = adjT
        + ((size_t)(4 * blockIdx.x) * 256 + (size_t)w * 64) * 1024 + (size_t)l * 8;

    f32x4 acc[4][4];
#pragma unroll
    for (int mi = 0; mi < 4; ++mi)
#pragma unroll
        for (int ni = 0; ni < 4; ++ni) acc[mi][ni] = (f32x4){0.f, 0.f, 0.f, 0.f};

    for (int kk = 0; kk < NN / 4; kk += 64) {
        const long kb = kbase + kk;
        short8 a[4][2], b[4][2];

#pragma unroll
        for (int mi = 0; mi < 4; ++mi) {
#pragma unroll
            for (int h = 0; h < 2; ++h)
                a[mi][h] = ntload_s8(At + (size_t)mi * 262144 + h * 512);
        }
        At += 1024;

#pragma unroll
        for (int ni = 0; ni < 4; ++ni)
#pragma unroll
            for (int h = 0; h < 2; ++h)
                b[ni][h] = *(const short8*)&xT[(size_t)(16 * ni + fr) * NN + kb + 32 * h];

#pragma unroll
        for (int mi = 0; mi < 4; ++mi)
#pragma unroll
            for (int ni = 0; ni < 4; ++ni)
#pragma unroll
                for (int h = 0; h < 2; ++h)
                    acc[mi][ni] = __builtin_amdgcn_mfma_f32_16x16x32_bf16(
                        a[mi][h], b[ni][h], acc[mi][ni], 0, 0, 0);
    }

    // ---- epilogue: two 32-row halves ----
#pragma unroll
    for (int half = 0; half < 2; ++half) {
        if (half) __syncthreads();
#pragma unroll
        for (int m2 = 0; m2 < 2; ++m2)
#pragma unroll
            for (int ni = 0; ni < 4; ++ni)
#pragma unroll
                for (int r = 0; r < 4; ++r)
                    buf[w][16 * m2 + 4 * fg + r][16 * ni + fr] = acc[2 * half + m2][ni][r];
        __syncthreads();
        const int row = l & 31;
        const int co  = 8 * (l >> 5);
#pragma unroll
        for (int cc = 0; cc < 8; ++cc) {
            int c = 16 * w + co + cc;
            float s = buf[0][row][c] + buf[1][row][c] + buf[2][row][c] + buf[3][row][c];
            size_t idx = (size_t)c * NN + row0 + 32 * half + row;
            xnT[idx] = f2bf(0.9f * s + 0.1f * bf2f(h0T[idx]));
        }
    }
}

// ---------------------------------------------------------------------------
// Fallback (tiny workspace): fp32 adj on the fly, untiled. Correct but slow.
// ---------------------------------------------------------------------------
__global__ __launch_bounds__(512, 2) void stepf_kernel(
        const float* __restrict__ adj,
        const unsigned short* __restrict__ xT,
        const unsigned short* __restrict__ h0T,
        unsigned short* __restrict__ xnT) {
    __shared__ float buf[8][32][66];

    const int t    = threadIdx.x;
    const int l    = t & 63;
    const int w    = t >> 6;
    const int fr   = l & 15;
    const int row0 = blockIdx.x * 32;

    const size_t a0 = (size_t)(row0 + fr) * NN;
    const size_t a1 = a0 + (size_t)16 * NN;
    const long   kbase = (long)w * (NN / 8) + 8 * (l >> 4);

    f32x4 acc[2][4];
#pragma unroll
    for (int mi = 0; mi < 2; ++mi)
#pragma unroll
        for (int ni = 0; ni < 4; ++ni) acc[mi][ni] = (f32x4){0.f, 0.f, 0.f, 0.f};

    for (int kk = 0; kk < NN / 8; kk += 64) {
        const long kb = kbase + kk;
        short8 a[2][2], b[4][2];
#pragma unroll
        for (int mi = 0; mi < 2; ++mi) {
            const size_t ab = (mi ? a1 : a0);
#pragma unroll
            for (int h = 0; h < 2; ++h) {
                f32x4 f0 = ntload_f4(&adj[ab + kb + 32 * h]);
                f32x4 f1 = ntload_f4(&adj[ab + kb + 32 * h + 4]);
                a[mi][h] = cvt8(f0, f1);
            }
        }
#pragma unroll
        for (int ni = 0; ni < 4; ++ni)
#pragma unroll
            for (int h = 0; h < 2; ++h)
                b[ni][h] = *(const short8*)&xT[(size_t)(16 * ni + fr) * NN + kb + 32 * h];
#pragma unroll
        for (int mi = 0; mi < 2; ++mi)
#pragma unroll
            for (int ni = 0; ni < 4; ++ni)
#pragma unroll
                for (int h = 0; h < 2; ++h)
                    acc[mi][ni] = __builtin_amdgcn_mfma_f32_16x16x32_bf16(
                        a[mi][h], b[ni][h], acc[mi][ni], 0, 0, 0);
    }
    finish32(buf, acc, t, l, w, row0, h0T, xnT);
}

// ---------------------------------------------------------------------------
// Final: h = x_cl @ W2; out_ls = log_softmax(h); out_x = x_cl fp32 row-major.
// ---------------------------------------------------------------------------
__global__ __launch_bounds__(256) void final_kernel(const unsigned short* __restrict__ xT,
                                                    const float* __restrict__ W2,
                                                    float* __restrict__ out_ls,
                                                    float* __restrict__ out_x) {
    __shared__ float LS[64][65];
    const int t  = threadIdx.x;
    const int rl = t & 63;
    const int w  = t >> 6;
    const int r0 = blockIdx.x * 64;

#pragma unroll
    for (int j = 0; j < 16; ++j) {
        int c = w * 16 + j;
        LS[c][rl] = bf2f(xT[(size_t)c * NN + r0 + rl]);
    }
    __syncthreads();

#pragma unroll
    for (int k2 = 0; k2 < 16; ++k2) {
        int idx = k2 * 256 + t;
        int row = idx >> 6, col = idx & 63;
        out_x[(size_t)(r0 + row) * NH + col] = LS[col][row];
    }

    float acc[NC];
    if (t < 64) {
#pragma unroll
        for (int j = 0; j < NC; ++j) acc[j] = 0.f;
        for (int c = 0; c < NH; ++c) {
            float xv = LS[c][t];
            const float* wr = W2 + (size_t)c * NC;
#pragma unroll
            for (int j = 0; j < NC; ++j) acc[j] = fmaf(xv, wr[j], acc[j]);
        }
        float m = acc[0];
#pragma unroll
        for (int j = 1; j < NC; ++j) m = fmaxf(m, acc[j]);
        float s = 0.f;
#pragma unroll
        for (int j = 0; j < NC; ++j) s += expf(acc[j] - m);
        float lg = m + logf(s);
#pragma unroll
        for (int j = 0; j < NC; ++j) acc[j] -= lg;
    }
    __syncthreads();
    if (t < 64) {
#pragma unroll
        for (int j = 0; j < NC; ++j) LS[t][j] = acc[j];
    }
    __syncthreads();
    for (int i = t; i < 64 * NC; i += 256) {
        int row = i / NC, j = i - row * NC;
        out_ls[(size_t)r0 * NC + i] = LS[row][j];
    }
}

// ---------------------------------------------------------------------------
extern "C" void kernel_launch(void* const* d_in, const int* in_sizes, int n_in,
                              void* d_out, int out_size, void* d_ws, size_t ws_size,
                              hipStream_t stream) {
    const float* x   = (const float*)d_in[0];
    const float* adj = (const float*)d_in[1];
    const float* W1  = (const float*)d_in[2];
    const float* W2  = (const float*)d_in[3];

    float* out_ls = (float*)d_out;                      // 16384*40 fp32
    float* out_x  = out_ls + (size_t)NN * NC;           // 16384*64 fp32

    const size_t xbytes = (size_t)NN * NH * sizeof(unsigned short);  // 2 MiB
    char* ws = (char*)d_ws;

    unsigned short *h0T, *xa, *xb;
    size_t used;
    if (ws_size >= 3 * xbytes) {
        h0T = (unsigned short*)ws;
        xa  = (unsigned short*)(ws + xbytes);
        xb  = (unsigned short*)(ws + 2 * xbytes);
        used = 3 * xbytes;
    } else {
        xa  = (unsigned short*)ws;
        xb  = xa + (size_t)NN * NH;
        h0T = (unsigned short*)out_ls;   // overwritten only by final_kernel
        used = 2 * xbytes;
    }
    used = (used + 255) & ~(size_t)255;

    unsigned short* adjT = nullptr;
    const size_t adjbytes = (size_t)NN * NN * sizeof(unsigned short); // 512 MiB
    if (ws_size >= used + adjbytes) adjT = (unsigned short*)(ws + used);

    h0_kernel<<<NN / 64, 256, 0, stream>>>(x, W1, h0T);

    unsigned short* cur = h0T;   // x0 = h0
    unsigned short* nxt = xa;
    for (int s = 0; s < KSTEPS; ++s) {
        if (adjT) {
            if (s == 0)
                step0_kernel<<<NN / 32, 512, 0, stream>>>(adj, adjT, cur, h0T, nxt);
            else
                stept_kernel<<<NN / 64, 256, 0, stream>>>(adjT, cur, h0T, nxt);
        } else {
            stepf_kernel<<<NN / 32, 512, 0, stream>>>(adj, cur, h0T, nxt);
        }
        unsigned short* tswap = (cur == h0T) ? xb : cur;
        cur = nxt;
        nxt = tswap;
    }

    final_kernel<<<NN / 64, 256, 0, stream>>>(cur, W2, out_ls, out_x);
}

// Round 5
// 1880.600 us; speedup vs baseline: 1.5010x; 1.5010x over previous
//
#include <hip/hip_runtime.h>

#define NN 16384
#define NF 512
#define NH 64
#define NC 40
#define KSTEPS 10
#define KSPLIT 8          // waves per block = K-split factor
#define BM 32             // rows per block

typedef __attribute__((ext_vector_type(8))) short short8;
typedef __attribute__((ext_vector_type(4))) float f32x4;

__device__ __forceinline__ unsigned short f2bf(float f) {
    unsigned int u = __float_as_uint(f);
    u += 0x7FFFu + ((u >> 16) & 1u);   // RNE
    return (unsigned short)(u >> 16);
}
__device__ __forceinline__ float bf2f(unsigned short h) {
    return __uint_as_float((unsigned int)h << 16);
}
__device__ __forceinline__ short8 cvt8(float4 f0, float4 f1) {
    short8 r;
    r[0] = (short)f2bf(f0.x); r[1] = (short)f2bf(f0.y);
    r[2] = (short)f2bf(f0.z); r[3] = (short)f2bf(f0.w);
    r[4] = (short)f2bf(f1.x); r[5] = (short)f2bf(f1.y);
    r[6] = (short)f2bf(f1.z); r[7] = (short)f2bf(f1.w);
    return r;
}
// non-temporal load: evict-first for the read-once A stream, so it doesn't
// displace the 2 MiB xT state from L2
__device__ __forceinline__ short8 ntload_s8(const unsigned short* p) {
    return __builtin_nontemporal_load((const short8*)p);
}

// ---------------------------------------------------------------------------
// h0T[c][r] = relu(x @ W1)[r][c]  (bf16, transposed layout)
// ---------------------------------------------------------------------------
__global__ __launch_bounds__(256) void h0_kernel(const float* __restrict__ x,
                                                 const float* __restrict__ W1,
                                                 unsigned short* __restrict__ h0T) {
    const int t  = threadIdx.x;
    const int rl = t & 63;
    const int w  = t >> 6;
    const size_t r = (size_t)blockIdx.x * 64 + rl;
    const float* xr = x + r * NF;

    float acc[16];
#pragma unroll
    for (int j = 0; j < 16; ++j) acc[j] = 0.f;

    for (int k = 0; k < NF; k += 4) {
        float4 xv = *(const float4*)&xr[k];
#pragma unroll
        for (int i = 0; i < 4; ++i) {
            float xs = (i == 0) ? xv.x : (i == 1) ? xv.y : (i == 2) ? xv.z : xv.w;
            const float* wr = W1 + (size_t)(k + i) * NH + w * 16;
#pragma unroll
            for (int j = 0; j < 16; ++j) acc[j] = fmaf(xs, wr[j], acc[j]);
        }
    }
#pragma unroll
    for (int j = 0; j < 16; ++j)
        h0T[(size_t)(w * 16 + j) * NN + r] = f2bf(fmaxf(acc[j], 0.f));
}

// ---------------------------------------------------------------------------
// Shared tail: combine 8 per-wave K-partials in LDS, fuse 0.9*s + 0.1*h0T,
// store bf16 to xnT (transposed layout). buf padded to 65 -> conflict-free.
// ---------------------------------------------------------------------------
__device__ __forceinline__ void finish_block(float buf[KSPLIT][BM][65],
                                             const f32x4 (&acc)[2][4],
                                             int t, int l, int w, int row0,
                                             const unsigned short* __restrict__ h0T,
                                             unsigned short* __restrict__ xnT) {
    const int fr = l & 15;
    const int fg = l >> 4;
#pragma unroll
    for (int mi = 0; mi < 2; ++mi)
#pragma unroll
        for (int ni = 0; ni < 4; ++ni)
#pragma unroll
            for (int r = 0; r < 4; ++r)
                buf[w][16 * mi + 4 * fg + r][16 * ni + fr] = acc[mi][ni][r];
    __syncthreads();

    const int col = t >> 3;
    const int rb  = 4 * (t & 7);
    float s0 = 0.f, s1 = 0.f, s2 = 0.f, s3 = 0.f;
#pragma unroll
    for (int ww = 0; ww < KSPLIT; ++ww) {
        s0 += buf[ww][rb + 0][col];
        s1 += buf[ww][rb + 1][col];
        s2 += buf[ww][rb + 2][col];
        s3 += buf[ww][rb + 3][col];
    }
    const size_t base = (size_t)col * NN + row0 + rb;
    ushort4 h4 = *(const ushort4*)&h0T[base];
    ushort4 o;
    o.x = f2bf(0.9f * s0 + 0.1f * bf2f(h4.x));
    o.y = f2bf(0.9f * s1 + 0.1f * bf2f(h4.y));
    o.z = f2bf(0.9f * s2 + 0.1f * bf2f(h4.z));
    o.w = f2bf(0.9f * s3 + 0.1f * bf2f(h4.w));
    *(ushort4*)&xnT[base] = o;
}

// ---------------------------------------------------------------------------
// Step 0 (fused): read adj fp32 (row-major), convert to bf16, MFMA, and store
// the bf16 fragments into the TILED layout adjT[rt][kt][h][lane][8]:
//   flat short idx = ((rt*256 + kt)*2 + h)*512 + lane*8 + j
//   element        = adj[rt*16 + (lane&15)][kt*64 + 32*h + 8*(lane>>4) + j]
// so steps 1..9 read A as wave-contiguous 1 KB chunks (DRAM-sequential).
// ---------------------------------------------------------------------------
__global__ __launch_bounds__(512, 2) void step0_kernel(
        const float* __restrict__ adj,
        unsigned short* __restrict__ adjT,
        const unsigned short* __restrict__ xT,
        const unsigned short* __restrict__ h0T,
        unsigned short* __restrict__ xnT) {
    __shared__ float buf[KSPLIT][BM][65];

    const int t    = threadIdx.x;
    const int l    = t & 63;
    const int w    = t >> 6;
    const int fr   = l & 15;
    const int fg   = l >> 4;
    const int row0 = blockIdx.x * BM;

    const size_t a0 = (size_t)(row0 + fr) * NN;
    const size_t a1 = a0 + (size_t)16 * NN;
    const long   kbase = (long)w * (NN / KSPLIT) + 8 * fg;

    f32x4 acc[2][4];
#pragma unroll
    for (int mi = 0; mi < 2; ++mi)
#pragma unroll
        for (int ni = 0; ni < 4; ++ni) acc[mi][ni] = (f32x4){0.f, 0.f, 0.f, 0.f};

    for (int kk = 0; kk < NN / KSPLIT; kk += 64) {
        const long kb    = kbase + kk;
        const size_t ktile = (size_t)w * 32 + (kk >> 6);
        short8 a[2][2], b[4][2];

#pragma unroll
        for (int mi = 0; mi < 2; ++mi) {
            const size_t ab = (mi ? a1 : a0);
#pragma unroll
            for (int h = 0; h < 2; ++h) {
                float4 f0 = *(const float4*)&adj[ab + kb + 32 * h];
                float4 f1 = *(const float4*)&adj[ab + kb + 32 * h + 4];
                a[mi][h] = cvt8(f0, f1);
                const size_t st = ((size_t)(2 * blockIdx.x + mi) * 256 + ktile) * 1024
                                  + (size_t)h * 512 + (size_t)l * 8;
                *(short8*)&adjT[st] = a[mi][h];
            }
        }
#pragma unroll
        for (int ni = 0; ni < 4; ++ni)
#pragma unroll
            for (int h = 0; h < 2; ++h)
                b[ni][h] = *(const short8*)&xT[(size_t)(16 * ni + fr) * NN + kb + 32 * h];

#pragma unroll
        for (int mi = 0; mi < 2; ++mi)
#pragma unroll
            for (int ni = 0; ni < 4; ++ni)
#pragma unroll
                for (int h = 0; h < 2; ++h)
                    acc[mi][ni] = __builtin_amdgcn_mfma_f32_16x16x32_bf16(
                        a[mi][h], b[ni][h], acc[mi][ni], 0, 0, 0);
    }
    finish_block(buf, acc, t, l, w, row0, h0T, xnT);
}

// ---------------------------------------------------------------------------
// Steps 1..9: A from tiled adjT — per wave, two purely sequential streams,
// 1 KB fully-coalesced NON-TEMPORAL loads (single diff vs round 3: nt keeps
// the read-once A stream from evicting xT out of L2). Barrier-free K loop.
// ---------------------------------------------------------------------------
__global__ __launch_bounds__(512, 4) void stept_kernel(
        const unsigned short* __restrict__ adjT,
        const unsigned short* __restrict__ xT,
        const unsigned short* __restrict__ h0T,
        unsigned short* __restrict__ xnT) {
    __shared__ float buf[KSPLIT][BM][65];

    const int t    = threadIdx.x;
    const int l    = t & 63;
    const int w    = t >> 6;
    const int fr   = l & 15;
    const int row0 = blockIdx.x * BM;
    const long kbase = (long)w * (NN / KSPLIT) + 8 * (l >> 4);

    const unsigned short* At0 = adjT
        + ((size_t)(2 * blockIdx.x) * 256 + (size_t)w * 32) * 1024 + (size_t)l * 8;
    const unsigned short* At1 = At0 + (size_t)256 * 1024;   // rt+1

    f32x4 acc[2][4];
#pragma unroll
    for (int mi = 0; mi < 2; ++mi)
#pragma unroll
        for (int ni = 0; ni < 4; ++ni) acc[mi][ni] = (f32x4){0.f, 0.f, 0.f, 0.f};

    for (int kk = 0; kk < NN / KSPLIT; kk += 64) {
        const long kb = kbase + kk;
        short8 a[2][2], b[4][2];

        a[0][0] = ntload_s8(At0);
        a[0][1] = ntload_s8(At0 + 512);
        a[1][0] = ntload_s8(At1);
        a[1][1] = ntload_s8(At1 + 512);
        At0 += 1024;
        At1 += 1024;

#pragma unroll
        for (int ni = 0; ni < 4; ++ni)
#pragma unroll
            for (int h = 0; h < 2; ++h)
                b[ni][h] = *(const short8*)&xT[(size_t)(16 * ni + fr) * NN + kb + 32 * h];

#pragma unroll
        for (int mi = 0; mi < 2; ++mi)
#pragma unroll
            for (int ni = 0; ni < 4; ++ni)
#pragma unroll
                for (int h = 0; h < 2; ++h)
                    acc[mi][ni] = __builtin_amdgcn_mfma_f32_16x16x32_bf16(
                        a[mi][h], b[ni][h], acc[mi][ni], 0, 0, 0);
    }
    finish_block(buf, acc, t, l, w, row0, h0T, xnT);
}

// ---------------------------------------------------------------------------
// Fallback (tiny workspace): fp32 adj on the fly, untiled. Correct but slow.
// ---------------------------------------------------------------------------
__global__ __launch_bounds__(512, 4) void stepf_kernel(
        const float* __restrict__ adj,
        const unsigned short* __restrict__ xT,
        const unsigned short* __restrict__ h0T,
        unsigned short* __restrict__ xnT) {
    __shared__ float buf[KSPLIT][BM][65];

    const int t    = threadIdx.x;
    const int l    = t & 63;
    const int w    = t >> 6;
    const int fr   = l & 15;
    const int row0 = blockIdx.x * BM;

    const size_t a0 = (size_t)(row0 + fr) * NN;
    const size_t a1 = a0 + (size_t)16 * NN;
    const long   kbase = (long)w * (NN / KSPLIT) + 8 * (l >> 4);

    f32x4 acc[2][4];
#pragma unroll
    for (int mi = 0; mi < 2; ++mi)
#pragma unroll
        for (int ni = 0; ni < 4; ++ni) acc[mi][ni] = (f32x4){0.f, 0.f, 0.f, 0.f};

    for (int kk = 0; kk < NN / KSPLIT; kk += 64) {
        const long kb = kbase + kk;
        short8 a[2][2], b[4][2];
#pragma unroll
        for (int mi = 0; mi < 2; ++mi) {
            const size_t ab = (mi ? a1 : a0);
#pragma unroll
            for (int h = 0; h < 2; ++h) {
                float4 f0 = *(const float4*)&adj[ab + kb + 32 * h];
                float4 f1 = *(const float4*)&adj[ab + kb + 32 * h + 4];
                a[mi][h] = cvt8(f0, f1);
            }
        }
#pragma unroll
        for (int ni = 0; ni < 4; ++ni)
#pragma unroll
            for (int h = 0; h < 2; ++h)
                b[ni][h] = *(const short8*)&xT[(size_t)(16 * ni + fr) * NN + kb + 32 * h];
#pragma unroll
        for (int mi = 0; mi < 2; ++mi)
#pragma unroll
            for (int ni = 0; ni < 4; ++ni)
#pragma unroll
                for (int h = 0; h < 2; ++h)
                    acc[mi][ni] = __builtin_amdgcn_mfma_f32_16x16x32_bf16(
                        a[mi][h], b[ni][h], acc[mi][ni], 0, 0, 0);
    }
    finish_block(buf, acc, t, l, w, row0, h0T, xnT);
}

// ---------------------------------------------------------------------------
// Final: h = x_cl @ W2; out_ls = log_softmax(h); out_x = x_cl fp32 row-major.
// ---------------------------------------------------------------------------
__global__ __launch_bounds__(256) void final_kernel(const unsigned short* __restrict__ xT,
                                                    const float* __restrict__ W2,
                                                    float* __restrict__ out_ls,
                                                    float* __restrict__ out_x) {
    __shared__ float LS[64][65];
    const int t  = threadIdx.x;
    const int rl = t & 63;
    const int w  = t >> 6;
    const int r0 = blockIdx.x * 64;

#pragma unroll
    for (int j = 0; j < 16; ++j) {
        int c = w * 16 + j;
        LS[c][rl] = bf2f(xT[(size_t)c * NN + r0 + rl]);
    }
    __syncthreads();

#pragma unroll
    for (int k2 = 0; k2 < 16; ++k2) {
        int idx = k2 * 256 + t;
        int row = idx >> 6, col = idx & 63;
        out_x[(size_t)(r0 + row) * NH + col] = LS[col][row];
    }

    float acc[NC];
    if (t < 64) {
#pragma unroll
        for (int j = 0; j < NC; ++j) acc[j] = 0.f;
        for (int c = 0; c < NH; ++c) {
            float xv = LS[c][t];
            const float* wr = W2 + (size_t)c * NC;
#pragma unroll
            for (int j = 0; j < NC; ++j) acc[j] = fmaf(xv, wr[j], acc[j]);
        }
        float m = acc[0];
#pragma unroll
        for (int j = 1; j < NC; ++j) m = fmaxf(m, acc[j]);
        float s = 0.f;
#pragma unroll
        for (int j = 0; j < NC; ++j) s += expf(acc[j] - m);
        float lg = m + logf(s);
#pragma unroll
        for (int j = 0; j < NC; ++j) acc[j] -= lg;
    }
    __syncthreads();
    if (t < 64) {
#pragma unroll
        for (int j = 0; j < NC; ++j) LS[t][j] = acc[j];
    }
    __syncthreads();
    for (int i = t; i < 64 * NC; i += 256) {
        int row = i / NC, j = i - row * NC;
        out_ls[(size_t)r0 * NC + i] = LS[row][j];
    }
}

// ---------------------------------------------------------------------------
extern "C" void kernel_launch(void* const* d_in, const int* in_sizes, int n_in,
                              void* d_out, int out_size, void* d_ws, size_t ws_size,
                              hipStream_t stream) {
    const float* x   = (const float*)d_in[0];
    const float* adj = (const float*)d_in[1];
    const float* W1  = (const float*)d_in[2];
    const float* W2  = (const float*)d_in[3];

    float* out_ls = (float*)d_out;                      // 16384*40 fp32
    float* out_x  = out_ls + (size_t)NN * NC;           // 16384*64 fp32

    const size_t xbytes = (size_t)NN * NH * sizeof(unsigned short);  // 2 MiB
    char* ws = (char*)d_ws;

    unsigned short *h0T, *xa, *xb;
    size_t used;
    if (ws_size >= 3 * xbytes) {
        h0T = (unsigned short*)ws;
        xa  = (unsigned short*)(ws + xbytes);
        xb  = (unsigned short*)(ws + 2 * xbytes);
        used = 3 * xbytes;
    } else {
        xa  = (unsigned short*)ws;
        xb  = xa + (size_t)NN * NH;
        h0T = (unsigned short*)out_ls;   // overwritten only by final_kernel
        used = 2 * xbytes;
    }
    used = (used + 255) & ~(size_t)255;

    unsigned short* adjT = nullptr;
    const size_t adjbytes = (size_t)NN * NN * sizeof(unsigned short); // 512 MiB
    if (ws_size >= used + adjbytes) adjT = (unsigned short*)(ws + used);

    h0_kernel<<<NN / 64, 256, 0, stream>>>(x, W1, h0T);

    unsigned short* cur = h0T;   // x0 = h0
    unsigned short* nxt = xa;
    for (int s = 0; s < KSTEPS; ++s) {
        if (adjT) {
            if (s == 0)
                step0_kernel<<<NN / BM, 512, 0, stream>>>(adj, adjT, cur, h0T, nxt);
            else
                stept_kernel<<<NN / BM, 512, 0, stream>>>(adjT, cur, h0T, nxt);
        } else {
            stepf_kernel<<<NN / BM, 512, 0, stream>>>(adj, cur, h0T, nxt);
        }
        unsigned short* tswap = (cur == h0T) ? xb : cur;
        cur = nxt;
        nxt = tswap;
    }

    final_kernel<<<NN / 64, 256, 0, stream>>>(cur, W2, out_ls, out_x);
}

// Round 6
// 1480.722 us; speedup vs baseline: 1.9064x; 1.2701x over previous
//
#include <hip/hip_runtime.h>

#define NN 16384
#define NF 512
#define NH 64
#define NC 40
#define KSTEPS 10
#define KSPLIT 8          // waves per block in step0/stepf
#define BM 32             // rows per block in step0/stepf
#define PKH 8             // K-split factor across blocks in stept

typedef __attribute__((ext_vector_type(8))) short short8;
typedef __attribute__((ext_vector_type(4))) float f32x4;

__device__ __forceinline__ unsigned short f2bf(float f) {
    unsigned int u = __float_as_uint(f);
    u += 0x7FFFu + ((u >> 16) & 1u);   // RNE
    return (unsigned short)(u >> 16);
}
__device__ __forceinline__ float bf2f(unsigned short h) {
    return __uint_as_float((unsigned int)h << 16);
}
__device__ __forceinline__ short8 cvt8(float4 f0, float4 f1) {
    short8 r;
    r[0] = (short)f2bf(f0.x); r[1] = (short)f2bf(f0.y);
    r[2] = (short)f2bf(f0.z); r[3] = (short)f2bf(f0.w);
    r[4] = (short)f2bf(f1.x); r[5] = (short)f2bf(f1.y);
    r[6] = (short)f2bf(f1.z); r[7] = (short)f2bf(f1.w);
    return r;
}
// non-temporal load for the read-once A stream
__device__ __forceinline__ short8 ntload_s8(const unsigned short* p) {
    return __builtin_nontemporal_load((const short8*)p);
}

// ---------------------------------------------------------------------------
// h0T[c][r] = relu(x @ W1)[r][c]  (bf16, transposed layout)
// ---------------------------------------------------------------------------
__global__ __launch_bounds__(256) void h0_kernel(const float* __restrict__ x,
                                                 const float* __restrict__ W1,
                                                 unsigned short* __restrict__ h0T) {
    const int t  = threadIdx.x;
    const int rl = t & 63;
    const int w  = t >> 6;
    const size_t r = (size_t)blockIdx.x * 64 + rl;
    const float* xr = x + r * NF;

    float acc[16];
#pragma unroll
    for (int j = 0; j < 16; ++j) acc[j] = 0.f;

    for (int k = 0; k < NF; k += 4) {
        float4 xv = *(const float4*)&xr[k];
#pragma unroll
        for (int i = 0; i < 4; ++i) {
            float xs = (i == 0) ? xv.x : (i == 1) ? xv.y : (i == 2) ? xv.z : xv.w;
            const float* wr = W1 + (size_t)(k + i) * NH + w * 16;
#pragma unroll
            for (int j = 0; j < 16; ++j) acc[j] = fmaf(xs, wr[j], acc[j]);
        }
    }
#pragma unroll
    for (int j = 0; j < 16; ++j)
        h0T[(size_t)(w * 16 + j) * NN + r] = f2bf(fmaxf(acc[j], 0.f));
}

// ---------------------------------------------------------------------------
// finish_block for BM=32 kernels (step0 / fallback): combine 8 per-wave
// K-partials in LDS, fuse 0.9*s + 0.1*h0T, store bf16 (transposed layout).
// ---------------------------------------------------------------------------
__device__ __forceinline__ void finish_block(float buf[KSPLIT][BM][65],
                                             const f32x4 (&acc)[2][4],
                                             int t, int l, int w, int row0,
                                             const unsigned short* __restrict__ h0T,
                                             unsigned short* __restrict__ xnT) {
    const int fr = l & 15;
    const int fg = l >> 4;
#pragma unroll
    for (int mi = 0; mi < 2; ++mi)
#pragma unroll
        for (int ni = 0; ni < 4; ++ni)
#pragma unroll
            for (int r = 0; r < 4; ++r)
                buf[w][16 * mi + 4 * fg + r][16 * ni + fr] = acc[mi][ni][r];
    __syncthreads();

    const int col = t >> 3;
    const int rb  = 4 * (t & 7);
    float s0 = 0.f, s1 = 0.f, s2 = 0.f, s3 = 0.f;
#pragma unroll
    for (int ww = 0; ww < KSPLIT; ++ww) {
        s0 += buf[ww][rb + 0][col];
        s1 += buf[ww][rb + 1][col];
        s2 += buf[ww][rb + 2][col];
        s3 += buf[ww][rb + 3][col];
    }
    const size_t base = (size_t)col * NN + row0 + rb;
    ushort4 h4 = *(const ushort4*)&h0T[base];
    ushort4 o;
    o.x = f2bf(0.9f * s0 + 0.1f * bf2f(h4.x));
    o.y = f2bf(0.9f * s1 + 0.1f * bf2f(h4.y));
    o.z = f2bf(0.9f * s2 + 0.1f * bf2f(h4.z));
    o.w = f2bf(0.9f * s3 + 0.1f * bf2f(h4.w));
    *(ushort4*)&xnT[base] = o;
}

// ---------------------------------------------------------------------------
// Step 0 (UNCHANGED from r5): read adj fp32, convert, MFMA, store bf16 frags
// into tiled adjT[mt16][kt64][h][lane][8]:
//   flat short idx = ((mt*256 + kt)*2 + h)*512 + lane*8 + j
//   element        = adj[mt*16 + (lane&15)][kt*64 + 32*h + 8*(lane>>4) + j]
// ---------------------------------------------------------------------------
__global__ __launch_bounds__(512, 2) void step0_kernel(
        const float* __restrict__ adj,
        unsigned short* __restrict__ adjT,
        const unsigned short* __restrict__ xT,
        const unsigned short* __restrict__ h0T,
        unsigned short* __restrict__ xnT) {
    __shared__ float buf[KSPLIT][BM][65];

    const int t    = threadIdx.x;
    const int l    = t & 63;
    const int w    = t >> 6;
    const int fr   = l & 15;
    const int fg   = l >> 4;
    const int row0 = blockIdx.x * BM;

    const size_t a0 = (size_t)(row0 + fr) * NN;
    const size_t a1 = a0 + (size_t)16 * NN;
    const long   kbase = (long)w * (NN / KSPLIT) + 8 * fg;

    f32x4 acc[2][4];
#pragma unroll
    for (int mi = 0; mi < 2; ++mi)
#pragma unroll
        for (int ni = 0; ni < 4; ++ni) acc[mi][ni] = (f32x4){0.f, 0.f, 0.f, 0.f};

    for (int kk = 0; kk < NN / KSPLIT; kk += 64) {
        const long kb    = kbase + kk;
        const size_t ktile = (size_t)w * 32 + (kk >> 6);
        short8 a[2][2], b[4][2];

#pragma unroll
        for (int mi = 0; mi < 2; ++mi) {
            const size_t ab = (mi ? a1 : a0);
#pragma unroll
            for (int h = 0; h < 2; ++h) {
                float4 f0 = *(const float4*)&adj[ab + kb + 32 * h];
                float4 f1 = *(const float4*)&adj[ab + kb + 32 * h + 4];
                a[mi][h] = cvt8(f0, f1);
                const size_t st = ((size_t)(2 * blockIdx.x + mi) * 256 + ktile) * 1024
                                  + (size_t)h * 512 + (size_t)l * 8;
                *(short8*)&adjT[st] = a[mi][h];
            }
        }
#pragma unroll
        for (int ni = 0; ni < 4; ++ni)
#pragma unroll
            for (int h = 0; h < 2; ++h)
                b[ni][h] = *(const short8*)&xT[(size_t)(16 * ni + fr) * NN + kb + 32 * h];

#pragma unroll
        for (int mi = 0; mi < 2; ++mi)
#pragma unroll
            for (int ni = 0; ni < 4; ++ni)
#pragma unroll
                for (int h = 0; h < 2; ++h)
                    acc[mi][ni] = __builtin_amdgcn_mfma_f32_16x16x32_bf16(
                        a[mi][h], b[ni][h], acc[mi][ni], 0, 0, 0);
    }
    finish_block(buf, acc, t, l, w, row0, h0T, xnT);
}

// ---------------------------------------------------------------------------
// Steps 1..9 (NEW): BM=256 rows/block, 8 waves split M (2 m-tiles each),
// K split 8x across blocks (kh = blockIdx & 7 == XCD id -> per-XCD B slab
// stays L2-hot). Per k64-iter: block stages the 8 B-fragments into LDS in
// FRAGMENT layout (1 short8 gload + 1 linear ds_write_b128 per thread,
// double-buffered, 1 barrier/iter); waves consume via linear ds_read_b128.
// B logical traffic: 1 GiB -> 128 MiB. A: unchanged tiled nt stream.
// Output: f32 partials P[kh][row][c]; combine_kernel reduces + epilogue.
// ---------------------------------------------------------------------------
__global__ __launch_bounds__(512, 4) void stept_kernel(
        const unsigned short* __restrict__ adjT,
        const unsigned short* __restrict__ xT,
        float* __restrict__ P) {
    __shared__ unsigned short BLF[2][512 * 8];   // 16 KiB, fragment-layout B

    const int t  = threadIdx.x;
    const int l  = t & 63;
    const int w  = t >> 6;           // wave id: owns rows w*32..+31 of the block
    const int fr = l & 15;
    const int fg = l >> 4;
    const int kh = blockIdx.x & 7;   // K-slab (and XCD) id
    const int rt = blockIdx.x >> 3;  // 256-row tile id
    const int kb0 = kh * (NN / PKH); // 2048-wide K slab

    // A: two tiled nt streams (m-tiles mt = rt*16 + 2w + {0,1})
    const unsigned short* At0 = adjT
        + (((size_t)(rt * 16 + 2 * w) * 256) + (size_t)(kh * 32)) * 1024 + (size_t)l * 8;
    const unsigned short* At1 = At0 + (size_t)256 * 1024;

    // B stage source for this thread: frag group g=w -> (ni=w>>1, h=w&1)
    const size_t bsrc = (size_t)(16 * (w >> 1) + fr) * NN + 32 * (w & 1) + 8 * fg;
    unsigned short* st0 = &BLF[0][t * 8];
    unsigned short* st1 = &BLF[1][t * 8];

    f32x4 acc[2][4];
#pragma unroll
    for (int mi = 0; mi < 2; ++mi)
#pragma unroll
        for (int ni = 0; ni < 4; ++ni) acc[mi][ni] = (f32x4){0.f, 0.f, 0.f, 0.f};

    // prologue: stage k-tile 0 into buf 0
    *(short8*)st0 = *(const short8*)&xT[bsrc + kb0];
    __syncthreads();

#pragma unroll 2
    for (int i = 0; i < 32; ++i) {
        const unsigned short* rdbuf = (i & 1) ? BLF[1] : BLF[0];
        unsigned short* stbuf = (i & 1) ? st0 : st1;
        if (i + 1 < 32)
            *(short8*)stbuf = *(const short8*)&xT[bsrc + kb0 + (i + 1) * 64];

        short8 a[2][2];
        a[0][0] = ntload_s8(At0);
        a[0][1] = ntload_s8(At0 + 512);
        a[1][0] = ntload_s8(At1);
        a[1][1] = ntload_s8(At1 + 512);
        At0 += 1024;
        At1 += 1024;

        short8 b[4][2];
#pragma unroll
        for (int ni = 0; ni < 4; ++ni)
#pragma unroll
            for (int h = 0; h < 2; ++h)
                b[ni][h] = *(const short8*)&rdbuf[(size_t)((ni * 2 + h) * 64 + l) * 8];

#pragma unroll
        for (int mi = 0; mi < 2; ++mi)
#pragma unroll
            for (int ni = 0; ni < 4; ++ni)
#pragma unroll
                for (int h = 0; h < 2; ++h)
                    acc[mi][ni] = __builtin_amdgcn_mfma_f32_16x16x32_bf16(
                        a[mi][h], b[ni][h], acc[mi][ni], 0, 0, 0);
        __syncthreads();
    }

    // write f32 partials: P[kh][grow][c], grow = rt*256 + w*32 + mi*16 + 4*fg + r
    const size_t rowbase = (size_t)rt * 256 + w * 32;
#pragma unroll
    for (int mi = 0; mi < 2; ++mi)
#pragma unroll
        for (int ni = 0; ni < 4; ++ni)
#pragma unroll
            for (int r = 0; r < 4; ++r)
                P[(((size_t)kh * NN) + rowbase + mi * 16 + 4 * fg + r) * 64 + 16 * ni + fr]
                    = acc[mi][ni][r];
}

// ---------------------------------------------------------------------------
// Combine: xnT[c][r] = bf16( 0.9 * sum_kh P[kh][r][c] + 0.1 * h0T[c][r] ).
// Block = 64 rows; P reads fully streaming; LDS 64x65 transpose; coalesced
// bf16 writes along r.
// ---------------------------------------------------------------------------
__global__ __launch_bounds__(256) void combine_kernel(
        const float* __restrict__ P,
        const unsigned short* __restrict__ h0T,
        unsigned short* __restrict__ xnT) {
    __shared__ float LS[64][65];
    const int t  = threadIdx.x;
    const int r0 = blockIdx.x * 64;

    {   // phase 1: sum partials, row-major
        const int rl = t >> 2;
        const int c0 = (t & 3) * 16;
        f32x4 s[4];
#pragma unroll
        for (int q = 0; q < 4; ++q) s[q] = (f32x4){0.f, 0.f, 0.f, 0.f};
#pragma unroll
        for (int kh = 0; kh < PKH; ++kh) {
            const float* p = &P[(((size_t)kh * NN) + r0 + rl) * 64 + c0];
#pragma unroll
            for (int q = 0; q < 4; ++q) s[q] += *(const f32x4*)&p[q * 4];
        }
#pragma unroll
        for (int q = 0; q < 4; ++q)
            *(f32x4*)&LS[rl][c0 + q * 4] = s[q];
    }
    __syncthreads();

    {   // phase 2: transpose + epilogue + bf16 store
        const int c  = t >> 2;
        const int rs = (t & 3) * 16;
        short8 v[2];
#pragma unroll
        for (int j = 0; j < 16; ++j) {
            float val = 0.9f * LS[rs + j][c]
                      + 0.1f * bf2f(h0T[(size_t)c * NN + r0 + rs + j]);
            v[j >> 3][j & 7] = (short)f2bf(val);
        }
        *(short8*)&xnT[(size_t)c * NN + r0 + rs] = v[0];
        *(short8*)&xnT[(size_t)c * NN + r0 + rs + 8] = v[1];
    }
}

// ---------------------------------------------------------------------------
// Fallback (tiny workspace): fp32 adj on the fly, untiled. Correct but slow.
// ---------------------------------------------------------------------------
__global__ __launch_bounds__(512, 4) void stepf_kernel(
        const float* __restrict__ adj,
        const unsigned short* __restrict__ xT,
        const unsigned short* __restrict__ h0T,
        unsigned short* __restrict__ xnT) {
    __shared__ float buf[KSPLIT][BM][65];

    const int t    = threadIdx.x;
    const int l    = t & 63;
    const int w    = t >> 6;
    const int fr   = l & 15;
    const int row0 = blockIdx.x * BM;

    const size_t a0 = (size_t)(row0 + fr) * NN;
    const size_t a1 = a0 + (size_t)16 * NN;
    const long   kbase = (long)w * (NN / KSPLIT) + 8 * (l >> 4);

    f32x4 acc[2][4];
#pragma unroll
    for (int mi = 0; mi < 2; ++mi)
#pragma unroll
        for (int ni = 0; ni < 4; ++ni) acc[mi][ni] = (f32x4){0.f, 0.f, 0.f, 0.f};

    for (int kk = 0; kk < NN / KSPLIT; kk += 64) {
        const long kb = kbase + kk;
        short8 a[2][2], b[4][2];
#pragma unroll
        for (int mi = 0; mi < 2; ++mi) {
            const size_t ab = (mi ? a1 : a0);
#pragma unroll
            for (int h = 0; h < 2; ++h) {
                float4 f0 = *(const float4*)&adj[ab + kb + 32 * h];
                float4 f1 = *(const float4*)&adj[ab + kb + 32 * h + 4];
                a[mi][h] = cvt8(f0, f1);
            }
        }
#pragma unroll
        for (int ni = 0; ni < 4; ++ni)
#pragma unroll
            for (int h = 0; h < 2; ++h)
                b[ni][h] = *(const short8*)&xT[(size_t)(16 * ni + fr) * NN + kb + 32 * h];
#pragma unroll
        for (int mi = 0; mi < 2; ++mi)
#pragma unroll
            for (int ni = 0; ni < 4; ++ni)
#pragma unroll
                for (int h = 0; h < 2; ++h)
                    acc[mi][ni] = __builtin_amdgcn_mfma_f32_16x16x32_bf16(
                        a[mi][h], b[ni][h], acc[mi][ni], 0, 0, 0);
    }
    finish_block(buf, acc, t, l, w, row0, h0T, xnT);
}

// ---------------------------------------------------------------------------
// Final: h = x_cl @ W2; out_ls = log_softmax(h); out_x = x_cl fp32 row-major.
// ---------------------------------------------------------------------------
__global__ __launch_bounds__(256) void final_kernel(const unsigned short* __restrict__ xT,
                                                    const float* __restrict__ W2,
                                                    float* __restrict__ out_ls,
                                                    float* __restrict__ out_x) {
    __shared__ float LS[64][65];
    const int t  = threadIdx.x;
    const int rl = t & 63;
    const int w  = t >> 6;
    const int r0 = blockIdx.x * 64;

#pragma unroll
    for (int j = 0; j < 16; ++j) {
        int c = w * 16 + j;
        LS[c][rl] = bf2f(xT[(size_t)c * NN + r0 + rl]);
    }
    __syncthreads();

#pragma unroll
    for (int k2 = 0; k2 < 16; ++k2) {
        int idx = k2 * 256 + t;
        int row = idx >> 6, col = idx & 63;
        out_x[(size_t)(r0 + row) * NH + col] = LS[col][row];
    }

    float acc[NC];
    if (t < 64) {
#pragma unroll
        for (int j = 0; j < NC; ++j) acc[j] = 0.f;
        for (int c = 0; c < NH; ++c) {
            float xv = LS[c][t];
            const float* wr = W2 + (size_t)c * NC;
#pragma unroll
            for (int j = 0; j < NC; ++j) acc[j] = fmaf(xv, wr[j], acc[j]);
        }
        float m = acc[0];
#pragma unroll
        for (int j = 1; j < NC; ++j) m = fmaxf(m, acc[j]);
        float s = 0.f;
#pragma unroll
        for (int j = 0; j < NC; ++j) s += expf(acc[j] - m);
        float lg = m + logf(s);
#pragma unroll
        for (int j = 0; j < NC; ++j) acc[j] -= lg;
    }
    __syncthreads();
    if (t < 64) {
#pragma unroll
        for (int j = 0; j < NC; ++j) LS[t][j] = acc[j];
    }
    __syncthreads();
    for (int i = t; i < 64 * NC; i += 256) {
        int row = i / NC, j = i - row * NC;
        out_ls[(size_t)r0 * NC + i] = LS[row][j];
    }
}

// ---------------------------------------------------------------------------
extern "C" void kernel_launch(void* const* d_in, const int* in_sizes, int n_in,
                              void* d_out, int out_size, void* d_ws, size_t ws_size,
                              hipStream_t stream) {
    const float* x   = (const float*)d_in[0];
    const float* adj = (const float*)d_in[1];
    const float* W1  = (const float*)d_in[2];
    const float* W2  = (const float*)d_in[3];

    float* out_ls = (float*)d_out;                      // 16384*40 fp32
    float* out_x  = out_ls + (size_t)NN * NC;           // 16384*64 fp32

    const size_t xbytes = (size_t)NN * NH * sizeof(unsigned short);  // 2 MiB
    char* ws = (char*)d_ws;

    unsigned short *h0T, *xa, *xb;
    size_t used;
    if (ws_size >= 3 * xbytes) {
        h0T = (unsigned short*)ws;
        xa  = (unsigned short*)(ws + xbytes);
        xb  = (unsigned short*)(ws + 2 * xbytes);
        used = 3 * xbytes;
    } else {
        xa  = (unsigned short*)ws;
        xb  = xa + (size_t)NN * NH;
        h0T = (unsigned short*)out_ls;   // overwritten only by final_kernel
        used = 2 * xbytes;
    }
    used = (used + 255) & ~(size_t)255;

    const size_t pbytes   = (size_t)PKH * NN * NH * sizeof(float);          // 32 MiB
    const size_t adjbytes = (size_t)NN * NN * sizeof(unsigned short);       // 512 MiB

    float* P = nullptr;
    unsigned short* adjT = nullptr;
    if (ws_size >= used + pbytes + adjbytes) {
        P    = (float*)(ws + used);
        adjT = (unsigned short*)(ws + used + pbytes);
    }

    h0_kernel<<<NN / 64, 256, 0, stream>>>(x, W1, h0T);

    unsigned short* cur = h0T;   // x0 = h0
    unsigned short* nxt = xa;
    for (int s = 0; s < KSTEPS; ++s) {
        if (adjT) {
            if (s == 0) {
                step0_kernel<<<NN / BM, 512, 0, stream>>>(adj, adjT, cur, h0T, nxt);
            } else {
                stept_kernel<<<(NN / 256) * PKH, 512, 0, stream>>>(adjT, cur, P);
                combine_kernel<<<NN / 64, 256, 0, stream>>>(P, h0T, nxt);
            }
        } else {
            stepf_kernel<<<NN / BM, 512, 0, stream>>>(adj, cur, h0T, nxt);
        }
        unsigned short* tswap = (cur == h0T) ? xb : cur;
        cur = nxt;
        nxt = tswap;
    }

    final_kernel<<<NN / 64, 256, 0, stream>>>(cur, W2, out_ls, out_x);
}

// Round 7
// 1049.191 us; speedup vs baseline: 2.6905x; 1.4113x over previous
//
#include <hip/hip_runtime.h>

#define NN 16384
#define NF 512
#define NH 64
#define NC 40
#define KSTEPS 10
#define KSPLIT 8          // waves per block in step0/stepf
#define BM 32             // rows per block in step0/stepf
#define PKH 8             // K-split factor across blocks in stept
#define ASCALE 8192.0f    // adj fp8 pre-scale (power of 2, exact)

typedef __attribute__((ext_vector_type(8))) short short8;
typedef __attribute__((ext_vector_type(4))) float f32x4;
typedef __attribute__((ext_vector_type(2))) long longx2;

__device__ __forceinline__ unsigned short f2bf(float f) {
    unsigned int u = __float_as_uint(f);
    u += 0x7FFFu + ((u >> 16) & 1u);   // RNE
    return (unsigned short)(u >> 16);
}
__device__ __forceinline__ float bf2f(unsigned short h) {
    return __uint_as_float((unsigned int)h << 16);
}
__device__ __forceinline__ short8 cvt8(float4 f0, float4 f1) {
    short8 r;
    r[0] = (short)f2bf(f0.x); r[1] = (short)f2bf(f0.y);
    r[2] = (short)f2bf(f0.z); r[3] = (short)f2bf(f0.w);
    r[4] = (short)f2bf(f1.x); r[5] = (short)f2bf(f1.y);
    r[6] = (short)f2bf(f1.z); r[7] = (short)f2bf(f1.w);
    return r;
}
// 4 f32 -> 4 packed OCP e4m3 bytes (HW cvt, RNE)
__device__ __forceinline__ int pack4fp8(float x0, float x1, float x2, float x3) {
    int r = __builtin_amdgcn_cvt_pk_fp8_f32(x0, x1, 0, false);
    return __builtin_amdgcn_cvt_pk_fp8_f32(x2, x3, r, true);
}
__device__ __forceinline__ longx2 ntload_l2(const unsigned char* p) {
    return __builtin_nontemporal_load((const longx2*)p);
}

// ---------------------------------------------------------------------------
// h0T[c][r] = relu(x @ W1)[r][c]  (bf16, transposed layout)
// ---------------------------------------------------------------------------
__global__ __launch_bounds__(256) void h0_kernel(const float* __restrict__ x,
                                                 const float* __restrict__ W1,
                                                 unsigned short* __restrict__ h0T) {
    const int t  = threadIdx.x;
    const int rl = t & 63;
    const int w  = t >> 6;
    const size_t r = (size_t)blockIdx.x * 64 + rl;
    const float* xr = x + r * NF;

    float acc[16];
#pragma unroll
    for (int j = 0; j < 16; ++j) acc[j] = 0.f;

    for (int k = 0; k < NF; k += 4) {
        float4 xv = *(const float4*)&xr[k];
#pragma unroll
        for (int i = 0; i < 4; ++i) {
            float xs = (i == 0) ? xv.x : (i == 1) ? xv.y : (i == 2) ? xv.z : xv.w;
            const float* wr = W1 + (size_t)(k + i) * NH + w * 16;
#pragma unroll
            for (int j = 0; j < 16; ++j) acc[j] = fmaf(xs, wr[j], acc[j]);
        }
    }
#pragma unroll
    for (int j = 0; j < 16; ++j)
        h0T[(size_t)(w * 16 + j) * NN + r] = f2bf(fmaxf(acc[j], 0.f));
}

// ---------------------------------------------------------------------------
// bf16 -> fp8 copy (h0T -> h0T8), coalesced grid-stride
// ---------------------------------------------------------------------------
__global__ __launch_bounds__(256) void cvtfp8_kernel(const unsigned short* __restrict__ in,
                                                     unsigned char* __restrict__ out,
                                                     long n8) {
    long i = (long)blockIdx.x * blockDim.x + threadIdx.x;
    if (i >= n8) return;
    short8 v = *(const short8*)&in[i * 8];
    int2 o;
    o.x = pack4fp8(bf2f((unsigned short)v[0]), bf2f((unsigned short)v[1]),
                   bf2f((unsigned short)v[2]), bf2f((unsigned short)v[3]));
    o.y = pack4fp8(bf2f((unsigned short)v[4]), bf2f((unsigned short)v[5]),
                   bf2f((unsigned short)v[6]), bf2f((unsigned short)v[7]));
    *(int2*)&out[i * 8] = o;
}

// ---------------------------------------------------------------------------
// finish_block (BM=32 kernels): combine 8 per-wave K-partials via LDS,
// fuse 0.9*s + 0.1*h0T, store bf16 xnT and (if given) fp8 xnT8.
// ---------------------------------------------------------------------------
__device__ __forceinline__ void finish_block(float buf[KSPLIT][BM][65],
                                             const f32x4 (&acc)[2][4],
                                             int t, int l, int w, int row0,
                                             const unsigned short* __restrict__ h0T,
                                             unsigned short* __restrict__ xnT,
                                             unsigned char* __restrict__ xnT8) {
    const int fr = l & 15;
    const int fg = l >> 4;
#pragma unroll
    for (int mi = 0; mi < 2; ++mi)
#pragma unroll
        for (int ni = 0; ni < 4; ++ni)
#pragma unroll
            for (int r = 0; r < 4; ++r)
                buf[w][16 * mi + 4 * fg + r][16 * ni + fr] = acc[mi][ni][r];
    __syncthreads();

    const int col = t >> 3;
    const int rb  = 4 * (t & 7);
    float s0 = 0.f, s1 = 0.f, s2 = 0.f, s3 = 0.f;
#pragma unroll
    for (int ww = 0; ww < KSPLIT; ++ww) {
        s0 += buf[ww][rb + 0][col];
        s1 += buf[ww][rb + 1][col];
        s2 += buf[ww][rb + 2][col];
        s3 += buf[ww][rb + 3][col];
    }
    const size_t base = (size_t)col * NN + row0 + rb;
    ushort4 h4 = *(const ushort4*)&h0T[base];
    float v0 = 0.9f * s0 + 0.1f * bf2f(h4.x);
    float v1 = 0.9f * s1 + 0.1f * bf2f(h4.y);
    float v2 = 0.9f * s2 + 0.1f * bf2f(h4.z);
    float v3 = 0.9f * s3 + 0.1f * bf2f(h4.w);
    ushort4 o;
    o.x = f2bf(v0); o.y = f2bf(v1); o.z = f2bf(v2); o.w = f2bf(v3);
    *(ushort4*)&xnT[base] = o;
    if (xnT8)
        *(int*)&xnT8[base] = pack4fp8(v0, v1, v2, v3);
}

// ---------------------------------------------------------------------------
// Step 0 (fused): read adj fp32, bf16-MFMA vs x0=h0 (bf16), and store fp8
// (x ASCALE) fragments into tiled adjT8:
//   byte addr = (mt*256 + kt)*1024 + l*16 + h*8 + j
//   element   = ASCALE * adj[mt*16 + (l&15)][kt*64 + 32*h + 8*(l>>4) + j]
// ---------------------------------------------------------------------------
__global__ __launch_bounds__(512, 2) void step0_kernel(
        const float* __restrict__ adj,
        unsigned char* __restrict__ adjT8,
        const unsigned short* __restrict__ xT,
        const unsigned short* __restrict__ h0T,
        unsigned short* __restrict__ xnT,
        unsigned char* __restrict__ xnT8) {
    __shared__ float buf[KSPLIT][BM][65];

    const int t    = threadIdx.x;
    const int l    = t & 63;
    const int w    = t >> 6;
    const int fr   = l & 15;
    const int fg   = l >> 4;
    const int row0 = blockIdx.x * BM;

    const size_t a0 = (size_t)(row0 + fr) * NN;
    const size_t a1 = a0 + (size_t)16 * NN;
    const long   kbase = (long)w * (NN / KSPLIT) + 8 * fg;

    f32x4 acc[2][4];
#pragma unroll
    for (int mi = 0; mi < 2; ++mi)
#pragma unroll
        for (int ni = 0; ni < 4; ++ni) acc[mi][ni] = (f32x4){0.f, 0.f, 0.f, 0.f};

    for (int kk = 0; kk < NN / KSPLIT; kk += 64) {
        const long kb      = kbase + kk;
        const size_t ktile = (size_t)w * 32 + (kk >> 6);
        short8 a[2][2], b[4][2];

#pragma unroll
        for (int mi = 0; mi < 2; ++mi) {
            const size_t ab = (mi ? a1 : a0);
            int4 pk;
#pragma unroll
            for (int h = 0; h < 2; ++h) {
                float4 f0 = *(const float4*)&adj[ab + kb + 32 * h];
                float4 f1 = *(const float4*)&adj[ab + kb + 32 * h + 4];
                a[mi][h] = cvt8(f0, f1);
                int plo = pack4fp8(ASCALE * f0.x, ASCALE * f0.y,
                                   ASCALE * f0.z, ASCALE * f0.w);
                int phi = pack4fp8(ASCALE * f1.x, ASCALE * f1.y,
                                   ASCALE * f1.z, ASCALE * f1.w);
                if (h == 0) { pk.x = plo; pk.y = phi; }
                else        { pk.z = plo; pk.w = phi; }
            }
            const size_t st = ((size_t)(2 * blockIdx.x + mi) * 256 + ktile) * 1024
                              + (size_t)l * 16;
            *(int4*)&adjT8[st] = pk;
        }
#pragma unroll
        for (int ni = 0; ni < 4; ++ni)
#pragma unroll
            for (int h = 0; h < 2; ++h)
                b[ni][h] = *(const short8*)&xT[(size_t)(16 * ni + fr) * NN + kb + 32 * h];

#pragma unroll
        for (int mi = 0; mi < 2; ++mi)
#pragma unroll
            for (int ni = 0; ni < 4; ++ni)
#pragma unroll
                for (int h = 0; h < 2; ++h)
                    acc[mi][ni] = __builtin_amdgcn_mfma_f32_16x16x32_bf16(
                        a[mi][h], b[ni][h], acc[mi][ni], 0, 0, 0);
    }
    finish_block(buf, acc, t, l, w, row0, h0T, xnT, xnT8);
}

// ---------------------------------------------------------------------------
// Steps 1..9: fp8 x fp8 MFMA. BM=256 rows/block, 8 waves split M, K split 8x
// across blocks (kh = bid&7). Per k64-iter: stage 4 KB fp8 B-tile into LDS
// (8 B gload + 8 B ds_write per thread, double-buffered); A = tiled fp8 nt
// stream, one 16-B load per m-tile per iter. Partials to P (f32).
// ---------------------------------------------------------------------------
__global__ __launch_bounds__(512, 4) void stept_kernel(
        const unsigned char* __restrict__ adjT8,
        const unsigned char* __restrict__ xT8,
        float* __restrict__ P) {
    __shared__ unsigned char BLF[2][4096];   // 8 KiB, fragment-layout fp8 B

    const int t  = threadIdx.x;
    const int l  = t & 63;
    const int w  = t >> 6;
    const int fr = l & 15;
    const int fg = l >> 4;
    const int kh = blockIdx.x & 7;
    const int rt = blockIdx.x >> 3;
    const int kb0 = kh * (NN / PKH);

    const unsigned char* At0 = adjT8
        + (((size_t)(rt * 16 + 2 * w) * 256) + (size_t)(kh * 32)) * 1024 + (size_t)l * 16;
    const unsigned char* At1 = At0 + (size_t)256 * 1024;

    // B stage source: frag (ni=w>>1, h=w&1), 8 contiguous fp8 per lane
    const size_t bsrc = (size_t)(16 * (w >> 1) + fr) * NN + 32 * (w & 1) + 8 * fg;
    unsigned char* st0 = &BLF[0][t * 8];
    unsigned char* st1 = &BLF[1][t * 8];

    f32x4 acc[2][4];
#pragma unroll
    for (int mi = 0; mi < 2; ++mi)
#pragma unroll
        for (int ni = 0; ni < 4; ++ni) acc[mi][ni] = (f32x4){0.f, 0.f, 0.f, 0.f};

    *(long*)st0 = *(const long*)&xT8[bsrc + kb0];
    __syncthreads();

#pragma unroll 2
    for (int i = 0; i < 32; ++i) {
        const unsigned char* rdbuf = (i & 1) ? BLF[1] : BLF[0];
        unsigned char* stbuf = (i & 1) ? st0 : st1;
        if (i + 1 < 32)
            *(long*)stbuf = *(const long*)&xT8[bsrc + kb0 + (i + 1) * 64];

        longx2 a0 = ntload_l2(At0);
        longx2 a1 = ntload_l2(At1);
        At0 += 1024;
        At1 += 1024;

        long b[4][2];
#pragma unroll
        for (int ni = 0; ni < 4; ++ni)
#pragma unroll
            for (int h = 0; h < 2; ++h)
                b[ni][h] = *(const long*)&rdbuf[(size_t)((ni * 2 + h) * 64 + l) * 8];

#pragma unroll
        for (int ni = 0; ni < 4; ++ni) {
            acc[0][ni] = __builtin_amdgcn_mfma_f32_16x16x32_fp8_fp8(a0.x, b[ni][0], acc[0][ni], 0, 0, 0);
            acc[0][ni] = __builtin_amdgcn_mfma_f32_16x16x32_fp8_fp8(a0.y, b[ni][1], acc[0][ni], 0, 0, 0);
            acc[1][ni] = __builtin_amdgcn_mfma_f32_16x16x32_fp8_fp8(a1.x, b[ni][0], acc[1][ni], 0, 0, 0);
            acc[1][ni] = __builtin_amdgcn_mfma_f32_16x16x32_fp8_fp8(a1.y, b[ni][1], acc[1][ni], 0, 0, 0);
        }
        __syncthreads();
    }

    const size_t rowbase = (size_t)rt * 256 + w * 32;
#pragma unroll
    for (int mi = 0; mi < 2; ++mi)
#pragma unroll
        for (int ni = 0; ni < 4; ++ni)
#pragma unroll
            for (int r = 0; r < 4; ++r)
                P[(((size_t)kh * NN) + rowbase + mi * 16 + 4 * fg + r) * 64 + 16 * ni + fr]
                    = acc[mi][ni][r];
}

// ---------------------------------------------------------------------------
// Combine: val = 0.9/ASCALE * sum_kh P + 0.1 * h0T; write bf16 xnT (state/
// output path) AND fp8 xnT8 (next step's B operand).
// ---------------------------------------------------------------------------
__global__ __launch_bounds__(256) void combine_kernel(
        const float* __restrict__ P,
        const unsigned short* __restrict__ h0T,
        unsigned short* __restrict__ xnT,
        unsigned char* __restrict__ xnT8) {
    __shared__ float LS[64][65];
    const int t  = threadIdx.x;
    const int r0 = blockIdx.x * 64;

    {   // phase 1: sum partials, row-major
        const int rl = t >> 2;
        const int c0 = (t & 3) * 16;
        f32x4 s[4];
#pragma unroll
        for (int q = 0; q < 4; ++q) s[q] = (f32x4){0.f, 0.f, 0.f, 0.f};
#pragma unroll
        for (int kh = 0; kh < PKH; ++kh) {
            const float* p = &P[(((size_t)kh * NN) + r0 + rl) * 64 + c0];
#pragma unroll
            for (int q = 0; q < 4; ++q) s[q] += *(const f32x4*)&p[q * 4];
        }
#pragma unroll
        for (int q = 0; q < 4; ++q)
            *(f32x4*)&LS[rl][c0 + q * 4] = s[q];
    }
    __syncthreads();

    {   // phase 2: transpose + epilogue + bf16/fp8 stores
        const int c  = t >> 2;
        const int rs = (t & 3) * 16;
        float vf[16];
        short8 v[2];
#pragma unroll
        for (int j = 0; j < 16; ++j) {
            vf[j] = (0.9f / ASCALE) * LS[rs + j][c]
                  + 0.1f * bf2f(h0T[(size_t)c * NN + r0 + rs + j]);
            v[j >> 3][j & 7] = (short)f2bf(vf[j]);
        }
        *(short8*)&xnT[(size_t)c * NN + r0 + rs]     = v[0];
        *(short8*)&xnT[(size_t)c * NN + r0 + rs + 8] = v[1];
        int4 pk;
        pk.x = pack4fp8(vf[0],  vf[1],  vf[2],  vf[3]);
        pk.y = pack4fp8(vf[4],  vf[5],  vf[6],  vf[7]);
        pk.z = pack4fp8(vf[8],  vf[9],  vf[10], vf[11]);
        pk.w = pack4fp8(vf[12], vf[13], vf[14], vf[15]);
        *(int4*)&xnT8[(size_t)c * NN + r0 + rs] = pk;
    }
}

// ---------------------------------------------------------------------------
// Fallback (tiny workspace): fp32 adj on the fly, bf16 MFMA, untiled.
// ---------------------------------------------------------------------------
__global__ __launch_bounds__(512, 4) void stepf_kernel(
        const float* __restrict__ adj,
        const unsigned short* __restrict__ xT,
        const unsigned short* __restrict__ h0T,
        unsigned short* __restrict__ xnT) {
    __shared__ float buf[KSPLIT][BM][65];

    const int t    = threadIdx.x;
    const int l    = t & 63;
    const int w    = t >> 6;
    const int fr   = l & 15;
    const int row0 = blockIdx.x * BM;

    const size_t a0 = (size_t)(row0 + fr) * NN;
    const size_t a1 = a0 + (size_t)16 * NN;
    const long   kbase = (long)w * (NN / KSPLIT) + 8 * (l >> 4);

    f32x4 acc[2][4];
#pragma unroll
    for (int mi = 0; mi < 2; ++mi)
#pragma unroll
        for (int ni = 0; ni < 4; ++ni) acc[mi][ni] = (f32x4){0.f, 0.f, 0.f, 0.f};

    for (int kk = 0; kk < NN / KSPLIT; kk += 64) {
        const long kb = kbase + kk;
        short8 a[2][2], b[4][2];
#pragma unroll
        for (int mi = 0; mi < 2; ++mi) {
            const size_t ab = (mi ? a1 : a0);
#pragma unroll
            for (int h = 0; h < 2; ++h) {
                float4 f0 = *(const float4*)&adj[ab + kb + 32 * h];
                float4 f1 = *(const float4*)&adj[ab + kb + 32 * h + 4];
                a[mi][h] = cvt8(f0, f1);
            }
        }
#pragma unroll
        for (int ni = 0; ni < 4; ++ni)
#pragma unroll
            for (int h = 0; h < 2; ++h)
                b[ni][h] = *(const short8*)&xT[(size_t)(16 * ni + fr) * NN + kb + 32 * h];
#pragma unroll
        for (int mi = 0; mi < 2; ++mi)
#pragma unroll
            for (int ni = 0; ni < 4; ++ni)
#pragma unroll
                for (int h = 0; h < 2; ++h)
                    acc[mi][ni] = __builtin_amdgcn_mfma_f32_16x16x32_bf16(
                        a[mi][h], b[ni][h], acc[mi][ni], 0, 0, 0);
    }
    finish_block(buf, acc, t, l, w, row0, h0T, xnT, nullptr);
}

// ---------------------------------------------------------------------------
// Final: h = x_cl @ W2; out_ls = log_softmax(h); out_x = x_cl fp32 row-major.
// ---------------------------------------------------------------------------
__global__ __launch_bounds__(256) void final_kernel(const unsigned short* __restrict__ xT,
                                                    const float* __restrict__ W2,
                                                    float* __restrict__ out_ls,
                                                    float* __restrict__ out_x) {
    __shared__ float LS[64][65];
    const int t  = threadIdx.x;
    const int rl = t & 63;
    const int w  = t >> 6;
    const int r0 = blockIdx.x * 64;

#pragma unroll
    for (int j = 0; j < 16; ++j) {
        int c = w * 16 + j;
        LS[c][rl] = bf2f(xT[(size_t)c * NN + r0 + rl]);
    }
    __syncthreads();

#pragma unroll
    for (int k2 = 0; k2 < 16; ++k2) {
        int idx = k2 * 256 + t;
        int row = idx >> 6, col = idx & 63;
        out_x[(size_t)(r0 + row) * NH + col] = LS[col][row];
    }

    float acc[NC];
    if (t < 64) {
#pragma unroll
        for (int j = 0; j < NC; ++j) acc[j] = 0.f;
        for (int c = 0; c < NH; ++c) {
            float xv = LS[c][t];
            const float* wr = W2 + (size_t)c * NC;
#pragma unroll
            for (int j = 0; j < NC; ++j) acc[j] = fmaf(xv, wr[j], acc[j]);
        }
        float m = acc[0];
#pragma unroll
        for (int j = 1; j < NC; ++j) m = fmaxf(m, acc[j]);
        float s = 0.f;
#pragma unroll
        for (int j = 0; j < NC; ++j) s += expf(acc[j] - m);
        float lg = m + logf(s);
#pragma unroll
        for (int j = 0; j < NC; ++j) acc[j] -= lg;
    }
    __syncthreads();
    if (t < 64) {
#pragma unroll
        for (int j = 0; j < NC; ++j) LS[t][j] = acc[j];
    }
    __syncthreads();
    for (int i = t; i < 64 * NC; i += 256) {
        int row = i / NC, j = i - row * NC;
        out_ls[(size_t)r0 * NC + i] = LS[row][j];
    }
}

// ---------------------------------------------------------------------------
extern "C" void kernel_launch(void* const* d_in, const int* in_sizes, int n_in,
                              void* d_out, int out_size, void* d_ws, size_t ws_size,
                              hipStream_t stream) {
    const float* x   = (const float*)d_in[0];
    const float* adj = (const float*)d_in[1];
    const float* W1  = (const float*)d_in[2];
    const float* W2  = (const float*)d_in[3];

    float* out_ls = (float*)d_out;                      // 16384*40 fp32
    float* out_x  = out_ls + (size_t)NN * NC;           // 16384*64 fp32

    const size_t xbytes  = (size_t)NN * NH * sizeof(unsigned short);  // 2 MiB
    const size_t x8bytes = (size_t)NN * NH;                           // 1 MiB
    char* ws = (char*)d_ws;

    unsigned short *h0T, *xa, *xb;
    unsigned char  *h0T8, *xa8, *xb8;
    size_t used;
    if (ws_size >= 3 * xbytes + 3 * x8bytes) {
        h0T  = (unsigned short*)ws;
        xa   = (unsigned short*)(ws + xbytes);
        xb   = (unsigned short*)(ws + 2 * xbytes);
        h0T8 = (unsigned char*)(ws + 3 * xbytes);
        xa8  = h0T8 + x8bytes;
        xb8  = xa8 + x8bytes;
        used = 3 * xbytes + 3 * x8bytes;
    } else {
        xa  = (unsigned short*)ws;
        xb  = xa + (size_t)NN * NH;
        h0T = (unsigned short*)out_ls;   // overwritten only by final_kernel
        h0T8 = xa8 = xb8 = nullptr;
        used = 2 * xbytes;
    }
    used = (used + 255) & ~(size_t)255;

    const size_t pbytes    = (size_t)PKH * NN * NH * sizeof(float);   // 32 MiB
    const size_t adj8bytes = (size_t)NN * NN;                         // 256 MiB

    float* P = nullptr;
    unsigned char* adjT8 = nullptr;
    if (h0T8 && ws_size >= used + pbytes + adj8bytes) {
        P     = (float*)(ws + used);
        adjT8 = (unsigned char*)(ws + used + pbytes);
    }

    h0_kernel<<<NN / 64, 256, 0, stream>>>(x, W1, h0T);

    unsigned short* cur  = h0T;   // x0 = h0
    unsigned short* nxt  = xa;
    unsigned char*  cur8 = h0T8;
    unsigned char*  nxt8 = xa8;

    if (adjT8)
        cvtfp8_kernel<<<(NN * NH / 8 + 255) / 256, 256, 0, stream>>>(
            h0T, h0T8, (long)NN * NH / 8);

    for (int s = 0; s < KSTEPS; ++s) {
        if (adjT8) {
            if (s == 0) {
                step0_kernel<<<NN / BM, 512, 0, stream>>>(adj, adjT8, cur, h0T, nxt, nxt8);
            } else {
                stept_kernel<<<(NN / 256) * PKH, 512, 0, stream>>>(adjT8, cur8, P);
                combine_kernel<<<NN / 64, 256, 0, stream>>>(P, h0T, nxt, nxt8);
            }
        } else {
            stepf_kernel<<<NN / BM, 512, 0, stream>>>(adj, cur, h0T, nxt);
        }
        unsigned short* ts  = (cur == h0T) ? xb : cur;
        unsigned char*  ts8 = (cur8 == h0T8) ? xb8 : cur8;
        cur = nxt;  nxt = ts;
        cur8 = nxt8; nxt8 = ts8;
    }

    final_kernel<<<NN / 64, 256, 0, stream>>>(cur, W2, out_ls, out_x);
}

// Round 8
// 1048.813 us; speedup vs baseline: 2.6914x; 1.0004x over previous
//
#include <hip/hip_runtime.h>

#define NN 16384
#define NF 512
#define NH 64
#define NC 40
#define KSTEPS 10
#define KSPLIT 8          // waves per block in step0/stepf
#define BM 32             // rows per block in step0/stepf
#define PKH 8             // K-split factor across blocks in stept
#define ASCALE 8192.0f    // adj fp8 pre-scale (power of 2, exact)

typedef __attribute__((ext_vector_type(8))) short short8;
typedef __attribute__((ext_vector_type(4))) float f32x4;
typedef __attribute__((ext_vector_type(2))) long longx2;

__device__ __forceinline__ unsigned short f2bf(float f) {
    unsigned int u = __float_as_uint(f);
    u += 0x7FFFu + ((u >> 16) & 1u);   // RNE
    return (unsigned short)(u >> 16);
}
__device__ __forceinline__ float bf2f(unsigned short h) {
    return __uint_as_float((unsigned int)h << 16);
}
__device__ __forceinline__ short8 cvt8(float4 f0, float4 f1) {
    short8 r;
    r[0] = (short)f2bf(f0.x); r[1] = (short)f2bf(f0.y);
    r[2] = (short)f2bf(f0.z); r[3] = (short)f2bf(f0.w);
    r[4] = (short)f2bf(f1.x); r[5] = (short)f2bf(f1.y);
    r[6] = (short)f2bf(f1.z); r[7] = (short)f2bf(f1.w);
    return r;
}
// 4 f32 -> 4 packed OCP e4m3 bytes (HW cvt, RNE)
__device__ __forceinline__ int pack4fp8(float x0, float x1, float x2, float x3) {
    int r = __builtin_amdgcn_cvt_pk_fp8_f32(x0, x1, 0, false);
    return __builtin_amdgcn_cvt_pk_fp8_f32(x2, x3, r, true);
}
__device__ __forceinline__ longx2 ntload_l2(const unsigned char* p) {
    return __builtin_nontemporal_load((const longx2*)p);
}

// ---------------------------------------------------------------------------
// h0T[c][r] = relu(x @ W1)[r][c]  (bf16, transposed layout)
// ---------------------------------------------------------------------------
__global__ __launch_bounds__(256) void h0_kernel(const float* __restrict__ x,
                                                 const float* __restrict__ W1,
                                                 unsigned short* __restrict__ h0T) {
    const int t  = threadIdx.x;
    const int rl = t & 63;
    const int w  = t >> 6;
    const size_t r = (size_t)blockIdx.x * 64 + rl;
    const float* xr = x + r * NF;

    float acc[16];
#pragma unroll
    for (int j = 0; j < 16; ++j) acc[j] = 0.f;

    for (int k = 0; k < NF; k += 4) {
        float4 xv = *(const float4*)&xr[k];
#pragma unroll
        for (int i = 0; i < 4; ++i) {
            float xs = (i == 0) ? xv.x : (i == 1) ? xv.y : (i == 2) ? xv.z : xv.w;
            const float* wr = W1 + (size_t)(k + i) * NH + w * 16;
#pragma unroll
            for (int j = 0; j < 16; ++j) acc[j] = fmaf(xs, wr[j], acc[j]);
        }
    }
#pragma unroll
    for (int j = 0; j < 16; ++j)
        h0T[(size_t)(w * 16 + j) * NN + r] = f2bf(fmaxf(acc[j], 0.f));
}

// ---------------------------------------------------------------------------
// bf16 -> fp8 copy (h0T -> h0T8), coalesced grid-stride
// ---------------------------------------------------------------------------
__global__ __launch_bounds__(256) void cvtfp8_kernel(const unsigned short* __restrict__ in,
                                                     unsigned char* __restrict__ out,
                                                     long n8) {
    long i = (long)blockIdx.x * blockDim.x + threadIdx.x;
    if (i >= n8) return;
    short8 v = *(const short8*)&in[i * 8];
    int2 o;
    o.x = pack4fp8(bf2f((unsigned short)v[0]), bf2f((unsigned short)v[1]),
                   bf2f((unsigned short)v[2]), bf2f((unsigned short)v[3]));
    o.y = pack4fp8(bf2f((unsigned short)v[4]), bf2f((unsigned short)v[5]),
                   bf2f((unsigned short)v[6]), bf2f((unsigned short)v[7]));
    *(int2*)&out[i * 8] = o;
}

// ---------------------------------------------------------------------------
// finish_block (BM=32 kernels): combine 8 per-wave K-partials via LDS,
// fuse 0.9*s + 0.1*h0T, store bf16 xnT and (if given) fp8 xnT8.
// ---------------------------------------------------------------------------
__device__ __forceinline__ void finish_block(float buf[KSPLIT][BM][65],
                                             const f32x4 (&acc)[2][4],
                                             int t, int l, int w, int row0,
                                             const unsigned short* __restrict__ h0T,
                                             unsigned short* __restrict__ xnT,
                                             unsigned char* __restrict__ xnT8) {
    const int fr = l & 15;
    const int fg = l >> 4;
#pragma unroll
    for (int mi = 0; mi < 2; ++mi)
#pragma unroll
        for (int ni = 0; ni < 4; ++ni)
#pragma unroll
            for (int r = 0; r < 4; ++r)
                buf[w][16 * mi + 4 * fg + r][16 * ni + fr] = acc[mi][ni][r];
    __syncthreads();

    const int col = t >> 3;
    const int rb  = 4 * (t & 7);
    float s0 = 0.f, s1 = 0.f, s2 = 0.f, s3 = 0.f;
#pragma unroll
    for (int ww = 0; ww < KSPLIT; ++ww) {
        s0 += buf[ww][rb + 0][col];
        s1 += buf[ww][rb + 1][col];
        s2 += buf[ww][rb + 2][col];
        s3 += buf[ww][rb + 3][col];
    }
    const size_t base = (size_t)col * NN + row0 + rb;
    ushort4 h4 = *(const ushort4*)&h0T[base];
    float v0 = 0.9f * s0 + 0.1f * bf2f(h4.x);
    float v1 = 0.9f * s1 + 0.1f * bf2f(h4.y);
    float v2 = 0.9f * s2 + 0.1f * bf2f(h4.z);
    float v3 = 0.9f * s3 + 0.1f * bf2f(h4.w);
    ushort4 o;
    o.x = f2bf(v0); o.y = f2bf(v1); o.z = f2bf(v2); o.w = f2bf(v3);
    *(ushort4*)&xnT[base] = o;
    if (xnT8)
        *(int*)&xnT8[base] = pack4fp8(v0, v1, v2, v3);
}

// ---------------------------------------------------------------------------
// Step 0 (fused): read adj fp32, bf16-MFMA vs x0=h0 (bf16), and store fp8
// (x ASCALE) fragments into tiled adjT8:
//   byte addr = (mt*256 + kt)*1024 + l*16 + h*8 + j
//   element   = ASCALE * adj[mt*16 + (l&15)][kt*64 + 32*h + 8*(l>>4) + j]
// ---------------------------------------------------------------------------
__global__ __launch_bounds__(512, 2) void step0_kernel(
        const float* __restrict__ adj,
        unsigned char* __restrict__ adjT8,
        const unsigned short* __restrict__ xT,
        const unsigned short* __restrict__ h0T,
        unsigned short* __restrict__ xnT,
        unsigned char* __restrict__ xnT8) {
    __shared__ float buf[KSPLIT][BM][65];

    const int t    = threadIdx.x;
    const int l    = t & 63;
    const int w    = t >> 6;
    const int fr   = l & 15;
    const int fg   = l >> 4;
    const int row0 = blockIdx.x * BM;

    const size_t a0 = (size_t)(row0 + fr) * NN;
    const size_t a1 = a0 + (size_t)16 * NN;
    const long   kbase = (long)w * (NN / KSPLIT) + 8 * fg;

    f32x4 acc[2][4];
#pragma unroll
    for (int mi = 0; mi < 2; ++mi)
#pragma unroll
        for (int ni = 0; ni < 4; ++ni) acc[mi][ni] = (f32x4){0.f, 0.f, 0.f, 0.f};

    for (int kk = 0; kk < NN / KSPLIT; kk += 64) {
        const long kb      = kbase + kk;
        const size_t ktile = (size_t)w * 32 + (kk >> 6);
        short8 a[2][2], b[4][2];

#pragma unroll
        for (int mi = 0; mi < 2; ++mi) {
            const size_t ab = (mi ? a1 : a0);
            int4 pk;
#pragma unroll
            for (int h = 0; h < 2; ++h) {
                float4 f0 = *(const float4*)&adj[ab + kb + 32 * h];
                float4 f1 = *(const float4*)&adj[ab + kb + 32 * h + 4];
                a[mi][h] = cvt8(f0, f1);
                int plo = pack4fp8(ASCALE * f0.x, ASCALE * f0.y,
                                   ASCALE * f0.z, ASCALE * f0.w);
                int phi = pack4fp8(ASCALE * f1.x, ASCALE * f1.y,
                                   ASCALE * f1.z, ASCALE * f1.w);
                if (h == 0) { pk.x = plo; pk.y = phi; }
                else        { pk.z = plo; pk.w = phi; }
            }
            const size_t st = ((size_t)(2 * blockIdx.x + mi) * 256 + ktile) * 1024
                              + (size_t)l * 16;
            *(int4*)&adjT8[st] = pk;
        }
#pragma unroll
        for (int ni = 0; ni < 4; ++ni)
#pragma unroll
            for (int h = 0; h < 2; ++h)
                b[ni][h] = *(const short8*)&xT[(size_t)(16 * ni + fr) * NN + kb + 32 * h];

#pragma unroll
        for (int mi = 0; mi < 2; ++mi)
#pragma unroll
            for (int ni = 0; ni < 4; ++ni)
#pragma unroll
                for (int h = 0; h < 2; ++h)
                    acc[mi][ni] = __builtin_amdgcn_mfma_f32_16x16x32_bf16(
                        a[mi][h], b[ni][h], acc[mi][ni], 0, 0, 0);
    }
    finish_block(buf, acc, t, l, w, row0, h0T, xnT, xnT8);
}

// ---------------------------------------------------------------------------
// Steps 1..9: fp8 x fp8 MFMA. BM=256 rows/block, 8 waves split M, K split 8x
// across blocks (kh = bid&7). Per k64-iter: stage 4 KB fp8 B-tile into LDS
// (8 B gload + 8 B ds_write per thread, double-buffered); A = tiled fp8 nt
// stream, one 16-B load per m-tile per iter. Partials to P (f32).
// ---------------------------------------------------------------------------
__global__ __launch_bounds__(512, 4) void stept_kernel(
        const unsigned char* __restrict__ adjT8,
        const unsigned char* __restrict__ xT8,
        float* __restrict__ P) {
    __shared__ unsigned char BLF[2][4096];   // 8 KiB, fragment-layout fp8 B

    const int t  = threadIdx.x;
    const int l  = t & 63;
    const int w  = t >> 6;
    const int fr = l & 15;
    const int fg = l >> 4;
    const int kh = blockIdx.x & 7;
    const int rt = blockIdx.x >> 3;
    const int kb0 = kh * (NN / PKH);

    const unsigned char* At0 = adjT8
        + (((size_t)(rt * 16 + 2 * w) * 256) + (size_t)(kh * 32)) * 1024 + (size_t)l * 16;
    const unsigned char* At1 = At0 + (size_t)256 * 1024;

    // B stage source: frag (ni=w>>1, h=w&1), 8 contiguous fp8 per lane
    const size_t bsrc = (size_t)(16 * (w >> 1) + fr) * NN + 32 * (w & 1) + 8 * fg;
    unsigned char* st0 = &BLF[0][t * 8];
    unsigned char* st1 = &BLF[1][t * 8];

    f32x4 acc[2][4];
#pragma unroll
    for (int mi = 0; mi < 2; ++mi)
#pragma unroll
        for (int ni = 0; ni < 4; ++ni) acc[mi][ni] = (f32x4){0.f, 0.f, 0.f, 0.f};

    *(long*)st0 = *(const long*)&xT8[bsrc + kb0];
    __syncthreads();

#pragma unroll 2
    for (int i = 0; i < 32; ++i) {
        const unsigned char* rdbuf = (i & 1) ? BLF[1] : BLF[0];
        unsigned char* stbuf = (i & 1) ? st0 : st1;
        if (i + 1 < 32)
            *(long*)stbuf = *(const long*)&xT8[bsrc + kb0 + (i + 1) * 64];

        longx2 a0 = ntload_l2(At0);
        longx2 a1 = ntload_l2(At1);
        At0 += 1024;
        At1 += 1024;

        long b[4][2];
#pragma unroll
        for (int ni = 0; ni < 4; ++ni)
#pragma unroll
            for (int h = 0; h < 2; ++h)
                b[ni][h] = *(const long*)&rdbuf[(size_t)((ni * 2 + h) * 64 + l) * 8];

#pragma unroll
        for (int ni = 0; ni < 4; ++ni) {
            acc[0][ni] = __builtin_amdgcn_mfma_f32_16x16x32_fp8_fp8(a0.x, b[ni][0], acc[0][ni], 0, 0, 0);
            acc[0][ni] = __builtin_amdgcn_mfma_f32_16x16x32_fp8_fp8(a0.y, b[ni][1], acc[0][ni], 0, 0, 0);
            acc[1][ni] = __builtin_amdgcn_mfma_f32_16x16x32_fp8_fp8(a1.x, b[ni][0], acc[1][ni], 0, 0, 0);
            acc[1][ni] = __builtin_amdgcn_mfma_f32_16x16x32_fp8_fp8(a1.y, b[ni][1], acc[1][ni], 0, 0, 0);
        }
        __syncthreads();
    }

    const size_t rowbase = (size_t)rt * 256 + w * 32;
#pragma unroll
    for (int mi = 0; mi < 2; ++mi)
#pragma unroll
        for (int ni = 0; ni < 4; ++ni)
#pragma unroll
            for (int r = 0; r < 4; ++r)
                P[(((size_t)kh * NN) + rowbase + mi * 16 + 4 * fg + r) * 64 + 16 * ni + fr]
                    = acc[mi][ni][r];
}

// ---------------------------------------------------------------------------
// Combine: val = 0.9/ASCALE * sum_kh P + 0.1 * h0T; write bf16 xnT (state/
// output path) AND fp8 xnT8 (next step's B operand).
// ---------------------------------------------------------------------------
__global__ __launch_bounds__(256) void combine_kernel(
        const float* __restrict__ P,
        const unsigned short* __restrict__ h0T,
        unsigned short* __restrict__ xnT,
        unsigned char* __restrict__ xnT8) {
    __shared__ float LS[64][65];
    const int t  = threadIdx.x;
    const int r0 = blockIdx.x * 64;

    {   // phase 1: sum partials, row-major
        const int rl = t >> 2;
        const int c0 = (t & 3) * 16;
        f32x4 s[4];
#pragma unroll
        for (int q = 0; q < 4; ++q) s[q] = (f32x4){0.f, 0.f, 0.f, 0.f};
#pragma unroll
        for (int kh = 0; kh < PKH; ++kh) {
            const float* p = &P[(((size_t)kh * NN) + r0 + rl) * 64 + c0];
#pragma unroll
            for (int q = 0; q < 4; ++q) s[q] += *(const f32x4*)&p[q * 4];
        }
#pragma unroll
        for (int q = 0; q < 4; ++q)
            *(f32x4*)&LS[rl][c0 + q * 4] = s[q];
    }
    __syncthreads();

    {   // phase 2: transpose + epilogue + bf16/fp8 stores
        const int c  = t >> 2;
        const int rs = (t & 3) * 16;
        float vf[16];
        short8 v[2];
#pragma unroll
        for (int j = 0; j < 16; ++j) {
            vf[j] = (0.9f / ASCALE) * LS[rs + j][c]
                  + 0.1f * bf2f(h0T[(size_t)c * NN + r0 + rs + j]);
            v[j >> 3][j & 7] = (short)f2bf(vf[j]);
        }
        *(short8*)&xnT[(size_t)c * NN + r0 + rs]     = v[0];
        *(short8*)&xnT[(size_t)c * NN + r0 + rs + 8] = v[1];
        int4 pk;
        pk.x = pack4fp8(vf[0],  vf[1],  vf[2],  vf[3]);
        pk.y = pack4fp8(vf[4],  vf[5],  vf[6],  vf[7]);
        pk.z = pack4fp8(vf[8],  vf[9],  vf[10], vf[11]);
        pk.w = pack4fp8(vf[12], vf[13], vf[14], vf[15]);
        *(int4*)&xnT8[(size_t)c * NN + r0 + rs] = pk;
    }
}

// ---------------------------------------------------------------------------
// Fallback (tiny workspace): fp32 adj on the fly, bf16 MFMA, untiled.
// ---------------------------------------------------------------------------
__global__ __launch_bounds__(512, 4) void stepf_kernel(
        const float* __restrict__ adj,
        const unsigned short* __restrict__ xT,
        const unsigned short* __restrict__ h0T,
        unsigned short* __restrict__ xnT) {
    __shared__ float buf[KSPLIT][BM][65];

    const int t    = threadIdx.x;
    const int l    = t & 63;
    const int w    = t >> 6;
    const int fr   = l & 15;
    const int row0 = blockIdx.x * BM;

    const size_t a0 = (size_t)(row0 + fr) * NN;
    const size_t a1 = a0 + (size_t)16 * NN;
    const long   kbase = (long)w * (NN / KSPLIT) + 8 * (l >> 4);

    f32x4 acc[2][4];
#pragma unroll
    for (int mi = 0; mi < 2; ++mi)
#pragma unroll
        for (int ni = 0; ni < 4; ++ni) acc[mi][ni] = (f32x4){0.f, 0.f, 0.f, 0.f};

    for (int kk = 0; kk < NN / KSPLIT; kk += 64) {
        const long kb = kbase + kk;
        short8 a[2][2], b[4][2];
#pragma unroll
        for (int mi = 0; mi < 2; ++mi) {
            const size_t ab = (mi ? a1 : a0);
#pragma unroll
            for (int h = 0; h < 2; ++h) {
                float4 f0 = *(const float4*)&adj[ab + kb + 32 * h];
                float4 f1 = *(const float4*)&adj[ab + kb + 32 * h + 4];
                a[mi][h] = cvt8(f0, f1);
            }
        }
#pragma unroll
        for (int ni = 0; ni < 4; ++ni)
#pragma unroll
            for (int h = 0; h < 2; ++h)
                b[ni][h] = *(const short8*)&xT[(size_t)(16 * ni + fr) * NN + kb + 32 * h];
#pragma unroll
        for (int mi = 0; mi < 2; ++mi)
#pragma unroll
            for (int ni = 0; ni < 4; ++ni)
#pragma unroll
                for (int h = 0; h < 2; ++h)
                    acc[mi][ni] = __builtin_amdgcn_mfma_f32_16x16x32_bf16(
                        a[mi][h], b[ni][h], acc[mi][ni], 0, 0, 0);
    }
    finish_block(buf, acc, t, l, w, row0, h0T, xnT, nullptr);
}

// ---------------------------------------------------------------------------
// Final: h = x_cl @ W2; out_ls = log_softmax(h); out_x = x_cl fp32 row-major.
// ---------------------------------------------------------------------------
__global__ __launch_bounds__(256) void final_kernel(const unsigned short* __restrict__ xT,
                                                    const float* __restrict__ W2,
                                                    float* __restrict__ out_ls,
                                                    float* __restrict__ out_x) {
    __shared__ float LS[64][65];
    const int t  = threadIdx.x;
    const int rl = t & 63;
    const int w  = t >> 6;
    const int r0 = blockIdx.x * 64;

#pragma unroll
    for (int j = 0; j < 16; ++j) {
        int c = w * 16 + j;
        LS[c][rl] = bf2f(xT[(size_t)c * NN + r0 + rl]);
    }
    __syncthreads();

#pragma unroll
    for (int k2 = 0; k2 < 16; ++k2) {
        int idx = k2 * 256 + t;
        int row = idx >> 6, col = idx & 63;
        out_x[(size_t)(r0 + row) * NH + col] = LS[col][row];
    }

    float acc[NC];
    if (t < 64) {
#pragma unroll
        for (int j = 0; j < NC; ++j) acc[j] = 0.f;
        for (int c = 0; c < NH; ++c) {
            float xv = LS[c][t];
            const float* wr = W2 + (size_t)c * NC;
#pragma unroll
            for (int j = 0; j < NC; ++j) acc[j] = fmaf(xv, wr[j], acc[j]);
        }
        float m = acc[0];
#pragma unroll
        for (int j = 1; j < NC; ++j) m = fmaxf(m, acc[j]);
        float s = 0.f;
#pragma unroll
        for (int j = 0; j < NC; ++j) s += expf(acc[j] - m);
        float lg = m + logf(s);
#pragma unroll
        for (int j = 0; j < NC; ++j) acc[j] -= lg;
    }
    __syncthreads();
    if (t < 64) {
#pragma unroll
        for (int j = 0; j < NC; ++j) LS[t][j] = acc[j];
    }
    __syncthreads();
    for (int i = t; i < 64 * NC; i += 256) {
        int row = i / NC, j = i - row * NC;
        out_ls[(size_t)r0 * NC + i] = LS[row][j];
    }
}

// ---------------------------------------------------------------------------
extern "C" void kernel_launch(void* const* d_in, const int* in_sizes, int n_in,
                              void* d_out, int out_size, void* d_ws, size_t ws_size,
                              hipStream_t stream) {
    const float* x   = (const float*)d_in[0];
    const float* adj = (const float*)d_in[1];
    const float* W1  = (const float*)d_in[2];
    const float* W2  = (const float*)d_in[3];

    float* out_ls = (float*)d_out;                      // 16384*40 fp32
    float* out_x  = out_ls + (size_t)NN * NC;           // 16384*64 fp32

    const size_t xbytes  = (size_t)NN * NH * sizeof(unsigned short);  // 2 MiB
    const size_t x8bytes = (size_t)NN * NH;                           // 1 MiB
    char* ws = (char*)d_ws;

    unsigned short *h0T, *xa, *xb;
    unsigned char  *h0T8, *xa8, *xb8;
    size_t used;
    if (ws_size >= 3 * xbytes + 3 * x8bytes) {
        h0T  = (unsigned short*)ws;
        xa   = (unsigned short*)(ws + xbytes);
        xb   = (unsigned short*)(ws + 2 * xbytes);
        h0T8 = (unsigned char*)(ws + 3 * xbytes);
        xa8  = h0T8 + x8bytes;
        xb8  = xa8 + x8bytes;
        used = 3 * xbytes + 3 * x8bytes;
    } else {
        xa  = (unsigned short*)ws;
        xb  = xa + (size_t)NN * NH;
        h0T = (unsigned short*)out_ls;   // overwritten only by final_kernel
        h0T8 = xa8 = xb8 = nullptr;
        used = 2 * xbytes;
    }
    used = (used + 255) & ~(size_t)255;

    const size_t pbytes    = (size_t)PKH * NN * NH * sizeof(float);   // 32 MiB
    const size_t adj8bytes = (size_t)NN * NN;                         // 256 MiB

    float* P = nullptr;
    unsigned char* adjT8 = nullptr;
    if (h0T8 && ws_size >= used + pbytes + adj8bytes) {
        P     = (float*)(ws + used);
        adjT8 = (unsigned char*)(ws + used + pbytes);
    }

    h0_kernel<<<NN / 64, 256, 0, stream>>>(x, W1, h0T);

    unsigned short* cur  = h0T;   // x0 = h0
    unsigned short* nxt  = xa;
    unsigned char*  cur8 = h0T8;
    unsigned char*  nxt8 = xa8;

    if (adjT8)
        cvtfp8_kernel<<<(NN * NH / 8 + 255) / 256, 256, 0, stream>>>(
            h0T, h0T8, (long)NN * NH / 8);

    for (int s = 0; s < KSTEPS; ++s) {
        if (adjT8) {
            if (s == 0) {
                step0_kernel<<<NN / BM, 512, 0, stream>>>(adj, adjT8, cur, h0T, nxt, nxt8);
            } else {
                stept_kernel<<<(NN / 256) * PKH, 512, 0, stream>>>(adjT8, cur8, P);
                combine_kernel<<<NN / 64, 256, 0, stream>>>(P, h0T, nxt, nxt8);
            }
        } else {
            stepf_kernel<<<NN / BM, 512, 0, stream>>>(adj, cur, h0T, nxt);
        }
        unsigned short* ts  = (cur == h0T) ? xb : cur;
        unsigned char*  ts8 = (cur8 == h0T8) ? xb8 : cur8;
        cur = nxt;  nxt = ts;
        cur8 = nxt8; nxt8 = ts8;
    }

    final_kernel<<<NN / 64, 256, 0, stream>>>(cur, W2, out_ls, out_x);
}

// Round 9
// 1048.087 us; speedup vs baseline: 2.6933x; 1.0007x over previous
//
#include <hip/hip_runtime.h>

#define NN 16384
#define NF 512
#define NH 64
#define NC 40
#define KSTEPS 10
#define KSPLIT 8          // waves per block in step0/stepf
#define BM 32             // rows per block in step0/stepf
#define PKH 8             // K-split factor across blocks in stept
#define ASCALE 8192.0f    // adj fp8 pre-scale (power of 2, exact)

typedef __attribute__((ext_vector_type(8))) short short8;
typedef __attribute__((ext_vector_type(4))) float f32x4;
typedef __attribute__((ext_vector_type(2))) long longx2;

__device__ __forceinline__ unsigned short f2bf(float f) {
    unsigned int u = __float_as_uint(f);
    u += 0x7FFFu + ((u >> 16) & 1u);   // RNE
    return (unsigned short)(u >> 16);
}
__device__ __forceinline__ float bf2f(unsigned short h) {
    return __uint_as_float((unsigned int)h << 16);
}
__device__ __forceinline__ short8 cvt8(float4 f0, float4 f1) {
    short8 r;
    r[0] = (short)f2bf(f0.x); r[1] = (short)f2bf(f0.y);
    r[2] = (short)f2bf(f0.z); r[3] = (short)f2bf(f0.w);
    r[4] = (short)f2bf(f1.x); r[5] = (short)f2bf(f1.y);
    r[6] = (short)f2bf(f1.z); r[7] = (short)f2bf(f1.w);
    return r;
}
// 4 f32 -> 4 packed OCP e4m3 bytes (HW cvt, RNE)
__device__ __forceinline__ int pack4fp8(float x0, float x1, float x2, float x3) {
    int r = __builtin_amdgcn_cvt_pk_fp8_f32(x0, x1, 0, false);
    return __builtin_amdgcn_cvt_pk_fp8_f32(x2, x3, r, true);
}
__device__ __forceinline__ longx2 ntload_l2(const unsigned char* p) {
    return __builtin_nontemporal_load((const longx2*)p);
}

// ---------------------------------------------------------------------------
// h0T[c][r] = relu(x @ W1)[r][c]  (bf16, transposed layout)
// ---------------------------------------------------------------------------
__global__ __launch_bounds__(256) void h0_kernel(const float* __restrict__ x,
                                                 const float* __restrict__ W1,
                                                 unsigned short* __restrict__ h0T) {
    const int t  = threadIdx.x;
    const int rl = t & 63;
    const int w  = t >> 6;
    const size_t r = (size_t)blockIdx.x * 64 + rl;
    const float* xr = x + r * NF;

    float acc[16];
#pragma unroll
    for (int j = 0; j < 16; ++j) acc[j] = 0.f;

    for (int k = 0; k < NF; k += 4) {
        float4 xv = *(const float4*)&xr[k];
#pragma unroll
        for (int i = 0; i < 4; ++i) {
            float xs = (i == 0) ? xv.x : (i == 1) ? xv.y : (i == 2) ? xv.z : xv.w;
            const float* wr = W1 + (size_t)(k + i) * NH + w * 16;
#pragma unroll
            for (int j = 0; j < 16; ++j) acc[j] = fmaf(xs, wr[j], acc[j]);
        }
    }
#pragma unroll
    for (int j = 0; j < 16; ++j)
        h0T[(size_t)(w * 16 + j) * NN + r] = f2bf(fmaxf(acc[j], 0.f));
}

// ---------------------------------------------------------------------------
// bf16 -> fp8 copy (h0T -> h0T8), coalesced grid-stride
// ---------------------------------------------------------------------------
__global__ __launch_bounds__(256) void cvtfp8_kernel(const unsigned short* __restrict__ in,
                                                     unsigned char* __restrict__ out,
                                                     long n8) {
    long i = (long)blockIdx.x * blockDim.x + threadIdx.x;
    if (i >= n8) return;
    short8 v = *(const short8*)&in[i * 8];
    int2 o;
    o.x = pack4fp8(bf2f((unsigned short)v[0]), bf2f((unsigned short)v[1]),
                   bf2f((unsigned short)v[2]), bf2f((unsigned short)v[3]));
    o.y = pack4fp8(bf2f((unsigned short)v[4]), bf2f((unsigned short)v[5]),
                   bf2f((unsigned short)v[6]), bf2f((unsigned short)v[7]));
    *(int2*)&out[i * 8] = o;
}

// ---------------------------------------------------------------------------
// finish_block (BM=32 kernels): combine 8 per-wave K-partials via LDS,
// fuse 0.9*s + 0.1*h0T, store bf16 xnT and (if given) fp8 xnT8.
// ---------------------------------------------------------------------------
__device__ __forceinline__ void finish_block(float buf[KSPLIT][BM][65],
                                             const f32x4 (&acc)[2][4],
                                             int t, int l, int w, int row0,
                                             const unsigned short* __restrict__ h0T,
                                             unsigned short* __restrict__ xnT,
                                             unsigned char* __restrict__ xnT8) {
    const int fr = l & 15;
    const int fg = l >> 4;
#pragma unroll
    for (int mi = 0; mi < 2; ++mi)
#pragma unroll
        for (int ni = 0; ni < 4; ++ni)
#pragma unroll
            for (int r = 0; r < 4; ++r)
                buf[w][16 * mi + 4 * fg + r][16 * ni + fr] = acc[mi][ni][r];
    __syncthreads();

    const int col = t >> 3;
    const int rb  = 4 * (t & 7);
    float s0 = 0.f, s1 = 0.f, s2 = 0.f, s3 = 0.f;
#pragma unroll
    for (int ww = 0; ww < KSPLIT; ++ww) {
        s0 += buf[ww][rb + 0][col];
        s1 += buf[ww][rb + 1][col];
        s2 += buf[ww][rb + 2][col];
        s3 += buf[ww][rb + 3][col];
    }
    const size_t base = (size_t)col * NN + row0 + rb;
    ushort4 h4 = *(const ushort4*)&h0T[base];
    float v0 = 0.9f * s0 + 0.1f * bf2f(h4.x);
    float v1 = 0.9f * s1 + 0.1f * bf2f(h4.y);
    float v2 = 0.9f * s2 + 0.1f * bf2f(h4.z);
    float v3 = 0.9f * s3 + 0.1f * bf2f(h4.w);
    ushort4 o;
    o.x = f2bf(v0); o.y = f2bf(v1); o.z = f2bf(v2); o.w = f2bf(v3);
    *(ushort4*)&xnT[base] = o;
    if (xnT8)
        *(int*)&xnT8[base] = pack4fp8(v0, v1, v2, v3);
}

// ---------------------------------------------------------------------------
// Step 0 (fused): read adj fp32, bf16-MFMA vs x0=h0 (bf16), and store fp8
// (x ASCALE) fragments into tiled adjT8:
//   byte addr = (mt*256 + kt)*1024 + l*16 + h*8 + j
//   element   = ASCALE * adj[mt*16 + (l&15)][kt*64 + 32*h + 8*(l>>4) + j]
// ---------------------------------------------------------------------------
__global__ __launch_bounds__(512, 2) void step0_kernel(
        const float* __restrict__ adj,
        unsigned char* __restrict__ adjT8,
        const unsigned short* __restrict__ xT,
        const unsigned short* __restrict__ h0T,
        unsigned short* __restrict__ xnT,
        unsigned char* __restrict__ xnT8) {
    __shared__ float buf[KSPLIT][BM][65];

    const int t    = threadIdx.x;
    const int l    = t & 63;
    const int w    = t >> 6;
    const int fr   = l & 15;
    const int fg   = l >> 4;
    const int row0 = blockIdx.x * BM;

    const size_t a0 = (size_t)(row0 + fr) * NN;
    const size_t a1 = a0 + (size_t)16 * NN;
    const long   kbase = (long)w * (NN / KSPLIT) + 8 * fg;

    f32x4 acc[2][4];
#pragma unroll
    for (int mi = 0; mi < 2; ++mi)
#pragma unroll
        for (int ni = 0; ni < 4; ++ni) acc[mi][ni] = (f32x4){0.f, 0.f, 0.f, 0.f};

    for (int kk = 0; kk < NN / KSPLIT; kk += 64) {
        const long kb      = kbase + kk;
        const size_t ktile = (size_t)w * 32 + (kk >> 6);
        short8 a[2][2], b[4][2];

#pragma unroll
        for (int mi = 0; mi < 2; ++mi) {
            const size_t ab = (mi ? a1 : a0);
            int4 pk;
#pragma unroll
            for (int h = 0; h < 2; ++h) {
                float4 f0 = *(const float4*)&adj[ab + kb + 32 * h];
                float4 f1 = *(const float4*)&adj[ab + kb + 32 * h + 4];
                a[mi][h] = cvt8(f0, f1);
                int plo = pack4fp8(ASCALE * f0.x, ASCALE * f0.y,
                                   ASCALE * f0.z, ASCALE * f0.w);
                int phi = pack4fp8(ASCALE * f1.x, ASCALE * f1.y,
                                   ASCALE * f1.z, ASCALE * f1.w);
                if (h == 0) { pk.x = plo; pk.y = phi; }
                else        { pk.z = plo; pk.w = phi; }
            }
            const size_t st = ((size_t)(2 * blockIdx.x + mi) * 256 + ktile) * 1024
                              + (size_t)l * 16;
            *(int4*)&adjT8[st] = pk;
        }
#pragma unroll
        for (int ni = 0; ni < 4; ++ni)
#pragma unroll
            for (int h = 0; h < 2; ++h)
                b[ni][h] = *(const short8*)&xT[(size_t)(16 * ni + fr) * NN + kb + 32 * h];

#pragma unroll
        for (int mi = 0; mi < 2; ++mi)
#pragma unroll
            for (int ni = 0; ni < 4; ++ni)
#pragma unroll
                for (int h = 0; h < 2; ++h)
                    acc[mi][ni] = __builtin_amdgcn_mfma_f32_16x16x32_bf16(
                        a[mi][h], b[ni][h], acc[mi][ni], 0, 0, 0);
    }
    finish_block(buf, acc, t, l, w, row0, h0T, xnT, xnT8);
}

// ---------------------------------------------------------------------------
// Steps 1..9: fp8 x fp8 MFMA. BM=256 rows/block, 8 waves split M, K split 8x
// across blocks (kh = bid&7). Per k64-iter: stage 4 KB fp8 B-tile into LDS
// (8 B gload + 8 B ds_write per thread, double-buffered); A = tiled fp8 nt
// stream, one 16-B load per m-tile per iter. Partials to P (f32).
// ---------------------------------------------------------------------------
__global__ __launch_bounds__(512, 4) void stept_kernel(
        const unsigned char* __restrict__ adjT8,
        const unsigned char* __restrict__ xT8,
        float* __restrict__ P) {
    __shared__ unsigned char BLF[2][4096];   // 8 KiB, fragment-layout fp8 B

    const int t  = threadIdx.x;
    const int l  = t & 63;
    const int w  = t >> 6;
    const int fr = l & 15;
    const int fg = l >> 4;
    const int kh = blockIdx.x & 7;
    const int rt = blockIdx.x >> 3;
    const int kb0 = kh * (NN / PKH);

    const unsigned char* At0 = adjT8
        + (((size_t)(rt * 16 + 2 * w) * 256) + (size_t)(kh * 32)) * 1024 + (size_t)l * 16;
    const unsigned char* At1 = At0 + (size_t)256 * 1024;

    // B stage source: frag (ni=w>>1, h=w&1), 8 contiguous fp8 per lane
    const size_t bsrc = (size_t)(16 * (w >> 1) + fr) * NN + 32 * (w & 1) + 8 * fg;
    unsigned char* st0 = &BLF[0][t * 8];
    unsigned char* st1 = &BLF[1][t * 8];

    f32x4 acc[2][4];
#pragma unroll
    for (int mi = 0; mi < 2; ++mi)
#pragma unroll
        for (int ni = 0; ni < 4; ++ni) acc[mi][ni] = (f32x4){0.f, 0.f, 0.f, 0.f};

    *(long*)st0 = *(const long*)&xT8[bsrc + kb0];
    __syncthreads();

#pragma unroll 2
    for (int i = 0; i < 32; ++i) {
        const unsigned char* rdbuf = (i & 1) ? BLF[1] : BLF[0];
        unsigned char* stbuf = (i & 1) ? st0 : st1;
        if (i + 1 < 32)
            *(long*)stbuf = *(const long*)&xT8[bsrc + kb0 + (i + 1) * 64];

        longx2 a0 = ntload_l2(At0);
        longx2 a1 = ntload_l2(At1);
        At0 += 1024;
        At1 += 1024;

        long b[4][2];
#pragma unroll
        for (int ni = 0; ni < 4; ++ni)
#pragma unroll
            for (int h = 0; h < 2; ++h)
                b[ni][h] = *(const long*)&rdbuf[(size_t)((ni * 2 + h) * 64 + l) * 8];

#pragma unroll
        for (int ni = 0; ni < 4; ++ni) {
            acc[0][ni] = __builtin_amdgcn_mfma_f32_16x16x32_fp8_fp8(a0.x, b[ni][0], acc[0][ni], 0, 0, 0);
            acc[0][ni] = __builtin_amdgcn_mfma_f32_16x16x32_fp8_fp8(a0.y, b[ni][1], acc[0][ni], 0, 0, 0);
            acc[1][ni] = __builtin_amdgcn_mfma_f32_16x16x32_fp8_fp8(a1.x, b[ni][0], acc[1][ni], 0, 0, 0);
            acc[1][ni] = __builtin_amdgcn_mfma_f32_16x16x32_fp8_fp8(a1.y, b[ni][1], acc[1][ni], 0, 0, 0);
        }
        __syncthreads();
    }

    const size_t rowbase = (size_t)rt * 256 + w * 32;
#pragma unroll
    for (int mi = 0; mi < 2; ++mi)
#pragma unroll
        for (int ni = 0; ni < 4; ++ni)
#pragma unroll
            for (int r = 0; r < 4; ++r)
                P[(((size_t)kh * NN) + rowbase + mi * 16 + 4 * fg + r) * 64 + 16 * ni + fr]
                    = acc[mi][ni][r];
}

// ---------------------------------------------------------------------------
// Combine: val = 0.9/ASCALE * sum_kh P + 0.1 * h0T; write bf16 xnT (state/
// output path) AND fp8 xnT8 (next step's B operand).
// ---------------------------------------------------------------------------
__global__ __launch_bounds__(256) void combine_kernel(
        const float* __restrict__ P,
        const unsigned short* __restrict__ h0T,
        unsigned short* __restrict__ xnT,
        unsigned char* __restrict__ xnT8) {
    __shared__ float LS[64][65];
    const int t  = threadIdx.x;
    const int r0 = blockIdx.x * 64;

    {   // phase 1: sum partials, row-major
        const int rl = t >> 2;
        const int c0 = (t & 3) * 16;
        f32x4 s[4];
#pragma unroll
        for (int q = 0; q < 4; ++q) s[q] = (f32x4){0.f, 0.f, 0.f, 0.f};
#pragma unroll
        for (int kh = 0; kh < PKH; ++kh) {
            const float* p = &P[(((size_t)kh * NN) + r0 + rl) * 64 + c0];
#pragma unroll
            for (int q = 0; q < 4; ++q) s[q] += *(const f32x4*)&p[q * 4];
        }
#pragma unroll
        for (int q = 0; q < 4; ++q)
            *(f32x4*)&LS[rl][c0 + q * 4] = s[q];
    }
    __syncthreads();

    {   // phase 2: transpose + epilogue + bf16/fp8 stores
        const int c  = t >> 2;
        const int rs = (t & 3) * 16;
        float vf[16];
        short8 v[2];
#pragma unroll
        for (int j = 0; j < 16; ++j) {
            vf[j] = (0.9f / ASCALE) * LS[rs + j][c]
                  + 0.1f * bf2f(h0T[(size_t)c * NN + r0 + rs + j]);
            v[j >> 3][j & 7] = (short)f2bf(vf[j]);
        }
        *(short8*)&xnT[(size_t)c * NN + r0 + rs]     = v[0];
        *(short8*)&xnT[(size_t)c * NN + r0 + rs + 8] = v[1];
        int4 pk;
        pk.x = pack4fp8(vf[0],  vf[1],  vf[2],  vf[3]);
        pk.y = pack4fp8(vf[4],  vf[5],  vf[6],  vf[7]);
        pk.z = pack4fp8(vf[8],  vf[9],  vf[10], vf[11]);
        pk.w = pack4fp8(vf[12], vf[13], vf[14], vf[15]);
        *(int4*)&xnT8[(size_t)c * NN + r0 + rs] = pk;
    }
}

// ---------------------------------------------------------------------------
// Fallback (tiny workspace): fp32 adj on the fly, bf16 MFMA, untiled.
// ---------------------------------------------------------------------------
__global__ __launch_bounds__(512, 4) void stepf_kernel(
        const float* __restrict__ adj,
        const unsigned short* __restrict__ xT,
        const unsigned short* __restrict__ h0T,
        unsigned short* __restrict__ xnT) {
    __shared__ float buf[KSPLIT][BM][65];

    const int t    = threadIdx.x;
    const int l    = t & 63;
    const int w    = t >> 6;
    const int fr   = l & 15;
    const int row0 = blockIdx.x * BM;

    const size_t a0 = (size_t)(row0 + fr) * NN;
    const size_t a1 = a0 + (size_t)16 * NN;
    const long   kbase = (long)w * (NN / KSPLIT) + 8 * (l >> 4);

    f32x4 acc[2][4];
#pragma unroll
    for (int mi = 0; mi < 2; ++mi)
#pragma unroll
        for (int ni = 0; ni < 4; ++ni) acc[mi][ni] = (f32x4){0.f, 0.f, 0.f, 0.f};

    for (int kk = 0; kk < NN / KSPLIT; kk += 64) {
        const long kb = kbase + kk;
        short8 a[2][2], b[4][2];
#pragma unroll
        for (int mi = 0; mi < 2; ++mi) {
            const size_t ab = (mi ? a1 : a0);
#pragma unroll
            for (int h = 0; h < 2; ++h) {
                float4 f0 = *(const float4*)&adj[ab + kb + 32 * h];
                float4 f1 = *(const float4*)&adj[ab + kb + 32 * h + 4];
                a[mi][h] = cvt8(f0, f1);
            }
        }
#pragma unroll
        for (int ni = 0; ni < 4; ++ni)
#pragma unroll
            for (int h = 0; h < 2; ++h)
                b[ni][h] = *(const short8*)&xT[(size_t)(16 * ni + fr) * NN + kb + 32 * h];
#pragma unroll
        for (int mi = 0; mi < 2; ++mi)
#pragma unroll
            for (int ni = 0; ni < 4; ++ni)
#pragma unroll
                for (int h = 0; h < 2; ++h)
                    acc[mi][ni] = __builtin_amdgcn_mfma_f32_16x16x32_bf16(
                        a[mi][h], b[ni][h], acc[mi][ni], 0, 0, 0);
    }
    finish_block(buf, acc, t, l, w, row0, h0T, xnT, nullptr);
}

// ---------------------------------------------------------------------------
// Final: h = x_cl @ W2; out_ls = log_softmax(h); out_x = x_cl fp32 row-major.
// ---------------------------------------------------------------------------
__global__ __launch_bounds__(256) void final_kernel(const unsigned short* __restrict__ xT,
                                                    const float* __restrict__ W2,
                                                    float* __restrict__ out_ls,
                                                    float* __restrict__ out_x) {
    __shared__ float LS[64][65];
    const int t  = threadIdx.x;
    const int rl = t & 63;
    const int w  = t >> 6;
    const int r0 = blockIdx.x * 64;

#pragma unroll
    for (int j = 0; j < 16; ++j) {
        int c = w * 16 + j;
        LS[c][rl] = bf2f(xT[(size_t)c * NN + r0 + rl]);
    }
    __syncthreads();

#pragma unroll
    for (int k2 = 0; k2 < 16; ++k2) {
        int idx = k2 * 256 + t;
        int row = idx >> 6, col = idx & 63;
        out_x[(size_t)(r0 + row) * NH + col] = LS[col][row];
    }

    float acc[NC];
    if (t < 64) {
#pragma unroll
        for (int j = 0; j < NC; ++j) acc[j] = 0.f;
        for (int c = 0; c < NH; ++c) {
            float xv = LS[c][t];
            const float* wr = W2 + (size_t)c * NC;
#pragma unroll
            for (int j = 0; j < NC; ++j) acc[j] = fmaf(xv, wr[j], acc[j]);
        }
        float m = acc[0];
#pragma unroll
        for (int j = 1; j < NC; ++j) m = fmaxf(m, acc[j]);
        float s = 0.f;
#pragma unroll
        for (int j = 0; j < NC; ++j) s += expf(acc[j] - m);
        float lg = m + logf(s);
#pragma unroll
        for (int j = 0; j < NC; ++j) acc[j] -= lg;
    }
    __syncthreads();
    if (t < 64) {
#pragma unroll
        for (int j = 0; j < NC; ++j) LS[t][j] = acc[j];
    }
    __syncthreads();
    for (int i = t; i < 64 * NC; i += 256) {
        int row = i / NC, j = i - row * NC;
        out_ls[(size_t)r0 * NC + i] = LS[row][j];
    }
}

// ---------------------------------------------------------------------------
extern "C" void kernel_launch(void* const* d_in, const int* in_sizes, int n_in,
                              void* d_out, int out_size, void* d_ws, size_t ws_size,
                              hipStream_t stream) {
    const float* x   = (const float*)d_in[0];
    const float* adj = (const float*)d_in[1];
    const float* W1  = (const float*)d_in[2];
    const float* W2  = (const float*)d_in[3];

    float* out_ls = (float*)d_out;                      // 16384*40 fp32
    float* out_x  = out_ls + (size_t)NN * NC;           // 16384*64 fp32

    const size_t xbytes  = (size_t)NN * NH * sizeof(unsigned short);  // 2 MiB
    const size_t x8bytes = (size_t)NN * NH;                           // 1 MiB
    char* ws = (char*)d_ws;

    unsigned short *h0T, *xa, *xb;
    unsigned char  *h0T8, *xa8, *xb8;
    size_t used;
    if (ws_size >= 3 * xbytes + 3 * x8bytes) {
        h0T  = (unsigned short*)ws;
        xa   = (unsigned short*)(ws + xbytes);
        xb   = (unsigned short*)(ws + 2 * xbytes);
        h0T8 = (unsigned char*)(ws + 3 * xbytes);
        xa8  = h0T8 + x8bytes;
        xb8  = xa8 + x8bytes;
        used = 3 * xbytes + 3 * x8bytes;
    } else {
        xa  = (unsigned short*)ws;
        xb  = xa + (size_t)NN * NH;
        h0T = (unsigned short*)out_ls;   // overwritten only by final_kernel
        h0T8 = xa8 = xb8 = nullptr;
        used = 2 * xbytes;
    }
    used = (used + 255) & ~(size_t)255;

    const size_t pbytes    = (size_t)PKH * NN * NH * sizeof(float);   // 32 MiB
    const size_t adj8bytes = (size_t)NN * NN;                         // 256 MiB

    float* P = nullptr;
    unsigned char* adjT8 = nullptr;
    if (h0T8 && ws_size >= used + pbytes + adj8bytes) {
        P     = (float*)(ws + used);
        adjT8 = (unsigned char*)(ws + used + pbytes);
    }

    h0_kernel<<<NN / 64, 256, 0, stream>>>(x, W1, h0T);

    unsigned short* cur  = h0T;   // x0 = h0
    unsigned short* nxt  = xa;
    unsigned char*  cur8 = h0T8;
    unsigned char*  nxt8 = xa8;

    if (adjT8)
        cvtfp8_kernel<<<(NN * NH / 8 + 255) / 256, 256, 0, stream>>>(
            h0T, h0T8, (long)NN * NH / 8);

    for (int s = 0; s < KSTEPS; ++s) {
        if (adjT8) {
            if (s == 0) {
                step0_kernel<<<NN / BM, 512, 0, stream>>>(adj, adjT8, cur, h0T, nxt, nxt8);
            } else {
                stept_kernel<<<(NN / 256) * PKH, 512, 0, stream>>>(adjT8, cur8, P);
                combine_kernel<<<NN / 64, 256, 0, stream>>>(P, h0T, nxt, nxt8);
            }
        } else {
            stepf_kernel<<<NN / BM, 512, 0, stream>>>(adj, cur, h0T, nxt);
        }
        unsigned short* ts  = (cur == h0T) ? xb : cur;
        unsigned char*  ts8 = (cur8 == h0T8) ? xb8 : cur8;
        cur = nxt;  nxt = ts;
        cur8 = nxt8; nxt8 = ts8;
    }

    final_kernel<<<NN / 64, 256, 0, stream>>>(cur, W2, out_ls, out_x);
}

// Round 10
// 1047.845 us; speedup vs baseline: 2.6939x; 1.0002x over previous
//
#include <hip/hip_runtime.h>

#define NN 16384
#define NF 512
#define NH 64
#define NC 40
#define KSTEPS 10
#define KSPLIT 8          // waves per block in step0/stepf
#define BM 32             // rows per block in step0/stepf
#define PKH 8             // K-split factor across blocks in stept
#define ASCALE 8192.0f    // adj fp8 pre-scale (power of 2, exact)

typedef __attribute__((ext_vector_type(8))) short short8;
typedef __attribute__((ext_vector_type(4))) float f32x4;
typedef __attribute__((ext_vector_type(2))) long longx2;

__device__ __forceinline__ unsigned short f2bf(float f) {
    unsigned int u = __float_as_uint(f);
    u += 0x7FFFu + ((u >> 16) & 1u);   // RNE
    return (unsigned short)(u >> 16);
}
__device__ __forceinline__ float bf2f(unsigned short h) {
    return __uint_as_float((unsigned int)h << 16);
}
__device__ __forceinline__ short8 cvt8(float4 f0, float4 f1) {
    short8 r;
    r[0] = (short)f2bf(f0.x); r[1] = (short)f2bf(f0.y);
    r[2] = (short)f2bf(f0.z); r[3] = (short)f2bf(f0.w);
    r[4] = (short)f2bf(f1.x); r[5] = (short)f2bf(f1.y);
    r[6] = (short)f2bf(f1.z); r[7] = (short)f2bf(f1.w);
    return r;
}
// 4 f32 -> 4 packed OCP e4m3 bytes (HW cvt, RNE)
__device__ __forceinline__ int pack4fp8(float x0, float x1, float x2, float x3) {
    int r = __builtin_amdgcn_cvt_pk_fp8_f32(x0, x1, 0, false);
    return __builtin_amdgcn_cvt_pk_fp8_f32(x2, x3, r, true);
}
__device__ __forceinline__ longx2 ntload_l2(const unsigned char* p) {
    return __builtin_nontemporal_load((const longx2*)p);
}

// ---------------------------------------------------------------------------
// h0T[c][r] = relu(x @ W1)[r][c]  (bf16, transposed layout)
// ---------------------------------------------------------------------------
__global__ __launch_bounds__(256) void h0_kernel(const float* __restrict__ x,
                                                 const float* __restrict__ W1,
                                                 unsigned short* __restrict__ h0T) {
    const int t  = threadIdx.x;
    const int rl = t & 63;
    const int w  = t >> 6;
    const size_t r = (size_t)blockIdx.x * 64 + rl;
    const float* xr = x + r * NF;

    float acc[16];
#pragma unroll
    for (int j = 0; j < 16; ++j) acc[j] = 0.f;

    for (int k = 0; k < NF; k += 4) {
        float4 xv = *(const float4*)&xr[k];
#pragma unroll
        for (int i = 0; i < 4; ++i) {
            float xs = (i == 0) ? xv.x : (i == 1) ? xv.y : (i == 2) ? xv.z : xv.w;
            const float* wr = W1 + (size_t)(k + i) * NH + w * 16;
#pragma unroll
            for (int j = 0; j < 16; ++j) acc[j] = fmaf(xs, wr[j], acc[j]);
        }
    }
#pragma unroll
    for (int j = 0; j < 16; ++j)
        h0T[(size_t)(w * 16 + j) * NN + r] = f2bf(fmaxf(acc[j], 0.f));
}

// ---------------------------------------------------------------------------
// bf16 -> fp8 copy (h0T -> h0T8), coalesced grid-stride
// ---------------------------------------------------------------------------
__global__ __launch_bounds__(256) void cvtfp8_kernel(const unsigned short* __restrict__ in,
                                                     unsigned char* __restrict__ out,
                                                     long n8) {
    long i = (long)blockIdx.x * blockDim.x + threadIdx.x;
    if (i >= n8) return;
    short8 v = *(const short8*)&in[i * 8];
    int2 o;
    o.x = pack4fp8(bf2f((unsigned short)v[0]), bf2f((unsigned short)v[1]),
                   bf2f((unsigned short)v[2]), bf2f((unsigned short)v[3]));
    o.y = pack4fp8(bf2f((unsigned short)v[4]), bf2f((unsigned short)v[5]),
                   bf2f((unsigned short)v[6]), bf2f((unsigned short)v[7]));
    *(int2*)&out[i * 8] = o;
}

// ---------------------------------------------------------------------------
// finish_block (BM=32 kernels): combine 8 per-wave K-partials via LDS,
// fuse 0.9*s + 0.1*h0T, store bf16 xnT and (if given) fp8 xnT8.
// ---------------------------------------------------------------------------
__device__ __forceinline__ void finish_block(float buf[KSPLIT][BM][65],
                                             const f32x4 (&acc)[2][4],
                                             int t, int l, int w, int row0,
                                             const unsigned short* __restrict__ h0T,
                                             unsigned short* __restrict__ xnT,
                                             unsigned char* __restrict__ xnT8) {
    const int fr = l & 15;
    const int fg = l >> 4;
#pragma unroll
    for (int mi = 0; mi < 2; ++mi)
#pragma unroll
        for (int ni = 0; ni < 4; ++ni)
#pragma unroll
            for (int r = 0; r < 4; ++r)
                buf[w][16 * mi + 4 * fg + r][16 * ni + fr] = acc[mi][ni][r];
    __syncthreads();

    const int col = t >> 3;
    const int rb  = 4 * (t & 7);
    float s0 = 0.f, s1 = 0.f, s2 = 0.f, s3 = 0.f;
#pragma unroll
    for (int ww = 0; ww < KSPLIT; ++ww) {
        s0 += buf[ww][rb + 0][col];
        s1 += buf[ww][rb + 1][col];
        s2 += buf[ww][rb + 2][col];
        s3 += buf[ww][rb + 3][col];
    }
    const size_t base = (size_t)col * NN + row0 + rb;
    ushort4 h4 = *(const ushort4*)&h0T[base];
    float v0 = 0.9f * s0 + 0.1f * bf2f(h4.x);
    float v1 = 0.9f * s1 + 0.1f * bf2f(h4.y);
    float v2 = 0.9f * s2 + 0.1f * bf2f(h4.z);
    float v3 = 0.9f * s3 + 0.1f * bf2f(h4.w);
    ushort4 o;
    o.x = f2bf(v0); o.y = f2bf(v1); o.z = f2bf(v2); o.w = f2bf(v3);
    *(ushort4*)&xnT[base] = o;
    if (xnT8)
        *(int*)&xnT8[base] = pack4fp8(v0, v1, v2, v3);
}

// ---------------------------------------------------------------------------
// Step 0 (fused): read adj fp32, bf16-MFMA vs x0=h0 (bf16), and store fp8
// (x ASCALE) fragments into tiled adjT8:
//   byte addr = (mt*256 + kt)*1024 + l*16 + h*8 + j
//   element   = ASCALE * adj[mt*16 + (l&15)][kt*64 + 32*h + 8*(l>>4) + j]
// ---------------------------------------------------------------------------
__global__ __launch_bounds__(512, 2) void step0_kernel(
        const float* __restrict__ adj,
        unsigned char* __restrict__ adjT8,
        const unsigned short* __restrict__ xT,
        const unsigned short* __restrict__ h0T,
        unsigned short* __restrict__ xnT,
        unsigned char* __restrict__ xnT8) {
    __shared__ float buf[KSPLIT][BM][65];

    const int t    = threadIdx.x;
    const int l    = t & 63;
    const int w    = t >> 6;
    const int fr   = l & 15;
    const int fg   = l >> 4;
    const int row0 = blockIdx.x * BM;

    const size_t a0 = (size_t)(row0 + fr) * NN;
    const size_t a1 = a0 + (size_t)16 * NN;
    const long   kbase = (long)w * (NN / KSPLIT) + 8 * fg;

    f32x4 acc[2][4];
#pragma unroll
    for (int mi = 0; mi < 2; ++mi)
#pragma unroll
        for (int ni = 0; ni < 4; ++ni) acc[mi][ni] = (f32x4){0.f, 0.f, 0.f, 0.f};

    for (int kk = 0; kk < NN / KSPLIT; kk += 64) {
        const long kb      = kbase + kk;
        const size_t ktile = (size_t)w * 32 + (kk >> 6);
        short8 a[2][2], b[4][2];

#pragma unroll
        for (int mi = 0; mi < 2; ++mi) {
            const size_t ab = (mi ? a1 : a0);
            int4 pk;
#pragma unroll
            for (int h = 0; h < 2; ++h) {
                float4 f0 = *(const float4*)&adj[ab + kb + 32 * h];
                float4 f1 = *(const float4*)&adj[ab + kb + 32 * h + 4];
                a[mi][h] = cvt8(f0, f1);
                int plo = pack4fp8(ASCALE * f0.x, ASCALE * f0.y,
                                   ASCALE * f0.z, ASCALE * f0.w);
                int phi = pack4fp8(ASCALE * f1.x, ASCALE * f1.y,
                                   ASCALE * f1.z, ASCALE * f1.w);
                if (h == 0) { pk.x = plo; pk.y = phi; }
                else        { pk.z = plo; pk.w = phi; }
            }
            const size_t st = ((size_t)(2 * blockIdx.x + mi) * 256 + ktile) * 1024
                              + (size_t)l * 16;
            *(int4*)&adjT8[st] = pk;
        }
#pragma unroll
        for (int ni = 0; ni < 4; ++ni)
#pragma unroll
            for (int h = 0; h < 2; ++h)
                b[ni][h] = *(const short8*)&xT[(size_t)(16 * ni + fr) * NN + kb + 32 * h];

#pragma unroll
        for (int mi = 0; mi < 2; ++mi)
#pragma unroll
            for (int ni = 0; ni < 4; ++ni)
#pragma unroll
                for (int h = 0; h < 2; ++h)
                    acc[mi][ni] = __builtin_amdgcn_mfma_f32_16x16x32_bf16(
                        a[mi][h], b[ni][h], acc[mi][ni], 0, 0, 0);
    }
    finish_block(buf, acc, t, l, w, row0, h0T, xnT, xnT8);
}

// ---------------------------------------------------------------------------
// Steps 1..9: fp8 x fp8 MFMA. BM=256 rows/block, 8 waves split M, K split 8x
// across blocks (kh = bid&7). Per k64-iter: stage 4 KB fp8 B-tile into LDS
// (8 B gload + 8 B ds_write per thread, double-buffered); A = tiled fp8 nt
// stream, one 16-B load per m-tile per iter. Partials to P (f32).
// ---------------------------------------------------------------------------
__global__ __launch_bounds__(512, 4) void stept_kernel(
        const unsigned char* __restrict__ adjT8,
        const unsigned char* __restrict__ xT8,
        float* __restrict__ P) {
    __shared__ unsigned char BLF[2][4096];   // 8 KiB, fragment-layout fp8 B

    const int t  = threadIdx.x;
    const int l  = t & 63;
    const int w  = t >> 6;
    const int fr = l & 15;
    const int fg = l >> 4;
    const int kh = blockIdx.x & 7;
    const int rt = blockIdx.x >> 3;
    const int kb0 = kh * (NN / PKH);

    const unsigned char* At0 = adjT8
        + (((size_t)(rt * 16 + 2 * w) * 256) + (size_t)(kh * 32)) * 1024 + (size_t)l * 16;
    const unsigned char* At1 = At0 + (size_t)256 * 1024;

    // B stage source: frag (ni=w>>1, h=w&1), 8 contiguous fp8 per lane
    const size_t bsrc = (size_t)(16 * (w >> 1) + fr) * NN + 32 * (w & 1) + 8 * fg;
    unsigned char* st0 = &BLF[0][t * 8];
    unsigned char* st1 = &BLF[1][t * 8];

    f32x4 acc[2][4];
#pragma unroll
    for (int mi = 0; mi < 2; ++mi)
#pragma unroll
        for (int ni = 0; ni < 4; ++ni) acc[mi][ni] = (f32x4){0.f, 0.f, 0.f, 0.f};

    *(long*)st0 = *(const long*)&xT8[bsrc + kb0];
    __syncthreads();

#pragma unroll 2
    for (int i = 0; i < 32; ++i) {
        const unsigned char* rdbuf = (i & 1) ? BLF[1] : BLF[0];
        unsigned char* stbuf = (i & 1) ? st0 : st1;
        if (i + 1 < 32)
            *(long*)stbuf = *(const long*)&xT8[bsrc + kb0 + (i + 1) * 64];

        longx2 a0 = ntload_l2(At0);
        longx2 a1 = ntload_l2(At1);
        At0 += 1024;
        At1 += 1024;

        long b[4][2];
#pragma unroll
        for (int ni = 0; ni < 4; ++ni)
#pragma unroll
            for (int h = 0; h < 2; ++h)
                b[ni][h] = *(const long*)&rdbuf[(size_t)((ni * 2 + h) * 64 + l) * 8];

#pragma unroll
        for (int ni = 0; ni < 4; ++ni) {
            acc[0][ni] = __builtin_amdgcn_mfma_f32_16x16x32_fp8_fp8(a0.x, b[ni][0], acc[0][ni], 0, 0, 0);
            acc[0][ni] = __builtin_amdgcn_mfma_f32_16x16x32_fp8_fp8(a0.y, b[ni][1], acc[0][ni], 0, 0, 0);
            acc[1][ni] = __builtin_amdgcn_mfma_f32_16x16x32_fp8_fp8(a1.x, b[ni][0], acc[1][ni], 0, 0, 0);
            acc[1][ni] = __builtin_amdgcn_mfma_f32_16x16x32_fp8_fp8(a1.y, b[ni][1], acc[1][ni], 0, 0, 0);
        }
        __syncthreads();
    }

    const size_t rowbase = (size_t)rt * 256 + w * 32;
#pragma unroll
    for (int mi = 0; mi < 2; ++mi)
#pragma unroll
        for (int ni = 0; ni < 4; ++ni)
#pragma unroll
            for (int r = 0; r < 4; ++r)
                P[(((size_t)kh * NN) + rowbase + mi * 16 + 4 * fg + r) * 64 + 16 * ni + fr]
                    = acc[mi][ni][r];
}

// ---------------------------------------------------------------------------
// Combine: val = 0.9/ASCALE * sum_kh P + 0.1 * h0T; write bf16 xnT (state/
// output path) AND fp8 xnT8 (next step's B operand).
// ---------------------------------------------------------------------------
__global__ __launch_bounds__(256) void combine_kernel(
        const float* __restrict__ P,
        const unsigned short* __restrict__ h0T,
        unsigned short* __restrict__ xnT,
        unsigned char* __restrict__ xnT8) {
    __shared__ float LS[64][65];
    const int t  = threadIdx.x;
    const int r0 = blockIdx.x * 64;

    {   // phase 1: sum partials, row-major
        const int rl = t >> 2;
        const int c0 = (t & 3) * 16;
        f32x4 s[4];
#pragma unroll
        for (int q = 0; q < 4; ++q) s[q] = (f32x4){0.f, 0.f, 0.f, 0.f};
#pragma unroll
        for (int kh = 0; kh < PKH; ++kh) {
            const float* p = &P[(((size_t)kh * NN) + r0 + rl) * 64 + c0];
#pragma unroll
            for (int q = 0; q < 4; ++q) s[q] += *(const f32x4*)&p[q * 4];
        }
#pragma unroll
        for (int q = 0; q < 4; ++q)
            *(f32x4*)&LS[rl][c0 + q * 4] = s[q];
    }
    __syncthreads();

    {   // phase 2: transpose + epilogue + bf16/fp8 stores
        const int c  = t >> 2;
        const int rs = (t & 3) * 16;
        float vf[16];
        short8 v[2];
#pragma unroll
        for (int j = 0; j < 16; ++j) {
            vf[j] = (0.9f / ASCALE) * LS[rs + j][c]
                  + 0.1f * bf2f(h0T[(size_t)c * NN + r0 + rs + j]);
            v[j >> 3][j & 7] = (short)f2bf(vf[j]);
        }
        *(short8*)&xnT[(size_t)c * NN + r0 + rs]     = v[0];
        *(short8*)&xnT[(size_t)c * NN + r0 + rs + 8] = v[1];
        int4 pk;
        pk.x = pack4fp8(vf[0],  vf[1],  vf[2],  vf[3]);
        pk.y = pack4fp8(vf[4],  vf[5],  vf[6],  vf[7]);
        pk.z = pack4fp8(vf[8],  vf[9],  vf[10], vf[11]);
        pk.w = pack4fp8(vf[12], vf[13], vf[14], vf[15]);
        *(int4*)&xnT8[(size_t)c * NN + r0 + rs] = pk;
    }
}

// ---------------------------------------------------------------------------
// Fallback (tiny workspace): fp32 adj on the fly, bf16 MFMA, untiled.
// ---------------------------------------------------------------------------
__global__ __launch_bounds__(512, 4) void stepf_kernel(
        const float* __restrict__ adj,
        const unsigned short* __restrict__ xT,
        const unsigned short* __restrict__ h0T,
        unsigned short* __restrict__ xnT) {
    __shared__ float buf[KSPLIT][BM][65];

    const int t    = threadIdx.x;
    const int l    = t & 63;
    const int w    = t >> 6;
    const int fr   = l & 15;
    const int row0 = blockIdx.x * BM;

    const size_t a0 = (size_t)(row0 + fr) * NN;
    const size_t a1 = a0 + (size_t)16 * NN;
    const long   kbase = (long)w * (NN / KSPLIT) + 8 * (l >> 4);

    f32x4 acc[2][4];
#pragma unroll
    for (int mi = 0; mi < 2; ++mi)
#pragma unroll
        for (int ni = 0; ni < 4; ++ni) acc[mi][ni] = (f32x4){0.f, 0.f, 0.f, 0.f};

    for (int kk = 0; kk < NN / KSPLIT; kk += 64) {
        const long kb = kbase + kk;
        short8 a[2][2], b[4][2];
#pragma unroll
        for (int mi = 0; mi < 2; ++mi) {
            const size_t ab = (mi ? a1 : a0);
#pragma unroll
            for (int h = 0; h < 2; ++h) {
                float4 f0 = *(const float4*)&adj[ab + kb + 32 * h];
                float4 f1 = *(const float4*)&adj[ab + kb + 32 * h + 4];
                a[mi][h] = cvt8(f0, f1);
            }
        }
#pragma unroll
        for (int ni = 0; ni < 4; ++ni)
#pragma unroll
            for (int h = 0; h < 2; ++h)
                b[ni][h] = *(const short8*)&xT[(size_t)(16 * ni + fr) * NN + kb + 32 * h];
#pragma unroll
        for (int mi = 0; mi < 2; ++mi)
#pragma unroll
            for (int ni = 0; ni < 4; ++ni)
#pragma unroll
                for (int h = 0; h < 2; ++h)
                    acc[mi][ni] = __builtin_amdgcn_mfma_f32_16x16x32_bf16(
                        a[mi][h], b[ni][h], acc[mi][ni], 0, 0, 0);
    }
    finish_block(buf, acc, t, l, w, row0, h0T, xnT, nullptr);
}

// ---------------------------------------------------------------------------
// Final: h = x_cl @ W2; out_ls = log_softmax(h); out_x = x_cl fp32 row-major.
// ---------------------------------------------------------------------------
__global__ __launch_bounds__(256) void final_kernel(const unsigned short* __restrict__ xT,
                                                    const float* __restrict__ W2,
                                                    float* __restrict__ out_ls,
                                                    float* __restrict__ out_x) {
    __shared__ float LS[64][65];
    const int t  = threadIdx.x;
    const int rl = t & 63;
    const int w  = t >> 6;
    const int r0 = blockIdx.x * 64;

#pragma unroll
    for (int j = 0; j < 16; ++j) {
        int c = w * 16 + j;
        LS[c][rl] = bf2f(xT[(size_t)c * NN + r0 + rl]);
    }
    __syncthreads();

#pragma unroll
    for (int k2 = 0; k2 < 16; ++k2) {
        int idx = k2 * 256 + t;
        int row = idx >> 6, col = idx & 63;
        out_x[(size_t)(r0 + row) * NH + col] = LS[col][row];
    }

    float acc[NC];
    if (t < 64) {
#pragma unroll
        for (int j = 0; j < NC; ++j) acc[j] = 0.f;
        for (int c = 0; c < NH; ++c) {
            float xv = LS[c][t];
            const float* wr = W2 + (size_t)c * NC;
#pragma unroll
            for (int j = 0; j < NC; ++j) acc[j] = fmaf(xv, wr[j], acc[j]);
        }
        float m = acc[0];
#pragma unroll
        for (int j = 1; j < NC; ++j) m = fmaxf(m, acc[j]);
        float s = 0.f;
#pragma unroll
        for (int j = 0; j < NC; ++j) s += expf(acc[j] - m);
        float lg = m + logf(s);
#pragma unroll
        for (int j = 0; j < NC; ++j) acc[j] -= lg;
    }
    __syncthreads();
    if (t < 64) {
#pragma unroll
        for (int j = 0; j < NC; ++j) LS[t][j] = acc[j];
    }
    __syncthreads();
    for (int i = t; i < 64 * NC; i += 256) {
        int row = i / NC, j = i - row * NC;
        out_ls[(size_t)r0 * NC + i] = LS[row][j];
    }
}

// ---------------------------------------------------------------------------
extern "C" void kernel_launch(void* const* d_in, const int* in_sizes, int n_in,
                              void* d_out, int out_size, void* d_ws, size_t ws_size,
                              hipStream_t stream) {
    const float* x   = (const float*)d_in[0];
    const float* adj = (const float*)d_in[1];
    const float* W1  = (const float*)d_in[2];
    const float* W2  = (const float*)d_in[3];

    float* out_ls = (float*)d_out;                      // 16384*40 fp32
    float* out_x  = out_ls + (size_t)NN * NC;           // 16384*64 fp32

    const size_t xbytes  = (size_t)NN * NH * sizeof(unsigned short);  // 2 MiB
    const size_t x8bytes = (size_t)NN * NH;                           // 1 MiB
    char* ws = (char*)d_ws;

    unsigned short *h0T, *xa, *xb;
    unsigned char  *h0T8, *xa8, *xb8;
    size_t used;
    if (ws_size >= 3 * xbytes + 3 * x8bytes) {
        h0T  = (unsigned short*)ws;
        xa   = (unsigned short*)(ws + xbytes);
        xb   = (unsigned short*)(ws + 2 * xbytes);
        h0T8 = (unsigned char*)(ws + 3 * xbytes);
        xa8  = h0T8 + x8bytes;
        xb8  = xa8 + x8bytes;
        used = 3 * xbytes + 3 * x8bytes;
    } else {
        xa  = (unsigned short*)ws;
        xb  = xa + (size_t)NN * NH;
        h0T = (unsigned short*)out_ls;   // overwritten only by final_kernel
        h0T8 = xa8 = xb8 = nullptr;
        used = 2 * xbytes;
    }
    used = (used + 255) & ~(size_t)255;

    const size_t pbytes    = (size_t)PKH * NN * NH * sizeof(float);   // 32 MiB
    const size_t adj8bytes = (size_t)NN * NN;                         // 256 MiB

    float* P = nullptr;
    unsigned char* adjT8 = nullptr;
    if (h0T8 && ws_size >= used + pbytes + adj8bytes) {
        P     = (float*)(ws + used);
        adjT8 = (unsigned char*)(ws + used + pbytes);
    }

    h0_kernel<<<NN / 64, 256, 0, stream>>>(x, W1, h0T);

    unsigned short* cur  = h0T;   // x0 = h0
    unsigned short* nxt  = xa;
    unsigned char*  cur8 = h0T8;
    unsigned char*  nxt8 = xa8;

    if (adjT8)
        cvtfp8_kernel<<<(NN * NH / 8 + 255) / 256, 256, 0, stream>>>(
            h0T, h0T8, (long)NN * NH / 8);

    for (int s = 0; s < KSTEPS; ++s) {
        if (adjT8) {
            if (s == 0) {
                step0_kernel<<<NN / BM, 512, 0, stream>>>(adj, adjT8, cur, h0T, nxt, nxt8);
            } else {
                stept_kernel<<<(NN / 256) * PKH, 512, 0, stream>>>(adjT8, cur8, P);
                combine_kernel<<<NN / 64, 256, 0, stream>>>(P, h0T, nxt, nxt8);
            }
        } else {
            stepf_kernel<<<NN / BM, 512, 0, stream>>>(adj, cur, h0T, nxt);
        }
        unsigned short* ts  = (cur == h0T) ? xb : cur;
        unsigned char*  ts8 = (cur8 == h0T8) ? xb8 : cur8;
        cur = nxt;  nxt = ts;
        cur8 = nxt8; nxt8 = ts8;
    }

    final_kernel<<<NN / 64, 256, 0, stream>>>(cur, W2, out_ls, out_x);
}